// Round 13
// baseline (366.550 us; speedup 1.0000x reference)
//
#include <hip/hip_runtime.h>
#include <hip/hip_bf16.h>

#define N_NODES 50000
#define N_EDGES 800000
#define G_GRAPHS 64
#define H_HEADS 4
#define D_DIM 128
#define HD 512
#define V_VOCAB 128
#define NEG_SLOPE 0.2f

typedef float f32x2v __attribute__((ext_vector_type(2)));
typedef float f32x4 __attribute__((ext_vector_type(4)));
typedef short s16x8 __attribute__((ext_vector_type(8)));
typedef _Float16 h16x2 __attribute__((ext_vector_type(2)));

static __device__ __forceinline__ float blo(unsigned int u) {
    union { float f; unsigned int i; } x; x.i = u << 16; return x.f;
}
static __device__ __forceinline__ float bhi(unsigned int u) {
    union { float f; unsigned int i; } x; x.i = u & 0xffff0000u; return x.f;
}
static __device__ __forceinline__ unsigned short f2b(float f) {
    union { float f; unsigned int i; } x; x.f = f;
    unsigned int r = x.i + 0x7fffu + ((x.i >> 16) & 1u);
    return (unsigned short)(r >> 16);
}
static __device__ __forceinline__ h16x2 u2h2(unsigned int u) {
    union { unsigned int u; h16x2 h; } c; c.u = u; return c.h;
}
static __device__ __forceinline__ unsigned int h22u(h16x2 h) {
    union { unsigned int u; h16x2 h; } c; c.h = h; return c.u;
}
static __device__ __forceinline__ h16x2 packf2(float lo, float hi) {
    union { __fp16 __attribute__((ext_vector_type(2))) p; h16x2 h; } c;
    c.p = __builtin_amdgcn_cvt_pkrtz(lo, hi);
    return c.h;
}

// unpack 4 fp8 (one dword) -> 2 h16x2
#if __has_builtin(__builtin_amdgcn_cvt_scalef32_pk_f16_fp8)
static __device__ __forceinline__ void fp8x4_to_h16(unsigned int u, h16x2& h0, h16x2& h1) {
    auto r0 = __builtin_amdgcn_cvt_scalef32_pk_f16_fp8((int)u, 1.0f, false);
    auto r1 = __builtin_amdgcn_cvt_scalef32_pk_f16_fp8((int)u, 1.0f, true);
    union { decltype(r0) p; h16x2 h; } c0, c1;
    c0.p = r0; c1.p = r1;
    h0 = c0.h; h1 = c1.h;
}
#else
static __device__ __forceinline__ void fp8x4_to_h16(unsigned int u, h16x2& h0, h16x2& h1) {
    f32x2v lo = __builtin_amdgcn_cvt_pk_f32_fp8(u, false);
    f32x2v hi = __builtin_amdgcn_cvt_pk_f32_fp8(u, true);
    h0 = packf2(lo.x, lo.y);
    h1 = packf2(hi.x, hi.y);
}
#endif

// butterfly-add over the 16-lane row via DPP (VALU pipe, no LDS latency)
template<int CTRL>
static __device__ __forceinline__ float dpp_add(float v) {
    union { float f; int i; } a, b;
    a.f = v;
    b.i = __builtin_amdgcn_mov_dpp(a.i, CTRL, 0xF, 0xF, true);
    return v + b.f;
}
static __device__ __forceinline__ float row16_sum(float p) {
    p = dpp_add<0xB1>(p);    // quad_perm [1,0,3,2]  : xor 1
    p = dpp_add<0x4E>(p);    // quad_perm [2,3,0,1]  : xor 2
    p = dpp_add<0x141>(p);   // ROW_HALF_MIRROR      : cross-quad in 8
    p = dpp_add<0x140>(p);   // ROW_MIRROR           : cross-8 in 16
    return p;
}

// ---------------- CSR build ----------------
__global__ void hist_kernel(const int* __restrict__ dst, int* __restrict__ counts,
                            float* __restrict__ pool) {
    if (blockIdx.x == 0 && threadIdx.x < G_GRAPHS) pool[threadIdx.x] = 0.f;
    int i = blockIdx.x * blockDim.x + threadIdx.x;
    if (i < N_EDGES) atomicAdd(&counts[dst[i]], 1);
}

__global__ void __launch_bounds__(256) scan1_kernel(const int* __restrict__ counts,
                                                    int* __restrict__ offsets,
                                                    int* __restrict__ bsum) {
    __shared__ int buf[256];
    int t = threadIdx.x, b = blockIdx.x;
    int i0 = (b * 256 + t) * 4;
    int v[4], c[4], s = 0;
    #pragma unroll
    for (int j = 0; j < 4; j++) {
        int idx = i0 + j;
        v[j] = (idx < N_NODES) ? counts[idx] : 0;
        s += v[j];
        c[j] = s;
    }
    buf[t] = s;
    __syncthreads();
    for (int off = 1; off < 256; off <<= 1) {
        int add = (t >= off) ? buf[t - off] : 0;
        __syncthreads();
        buf[t] += add;
        __syncthreads();
    }
    int ebase = (t > 0) ? buf[t - 1] : 0;
    #pragma unroll
    for (int j = 0; j < 4; j++) {
        int idx = i0 + j;
        if (idx < N_NODES) offsets[idx + 1] = ebase + c[j];
    }
    if (t == 0) bsum[b] = buf[255];
}

__global__ void __launch_bounds__(256) scan23_kernel(const int* __restrict__ counts,
                                                     int* __restrict__ offsets,
                                                     const int* __restrict__ bsum,
                                                     int* __restrict__ cursor) {
    __shared__ int sbase;
    int t = threadIdx.x, b = blockIdx.x;
    if (t < 64) {
        int v = (t < b) ? bsum[t] : 0;
        #pragma unroll
        for (int off = 1; off < 64; off <<= 1) v += __shfl_xor(v, off);
        if (t == 0) sbase = v;
    }
    __syncthreads();
    int base = sbase;
    int i0 = (b * 256 + t) * 4;
    #pragma unroll
    for (int j = 0; j < 4; j++) {
        int idx = i0 + j;
        if (idx < N_NODES) {
            int e = offsets[idx + 1] + base;
            offsets[idx + 1] = e;
            cursor[idx] = e - counts[idx];
        }
    }
    if (b == 0 && t == 0) offsets[0] = 0;
}

__global__ void scatter_kernel(const int* __restrict__ src, const int* __restrict__ dst,
                               int* __restrict__ cursor, int* __restrict__ csr_src) {
    int i = blockIdx.x * blockDim.x + threadIdx.x;
    if (i < N_EDGES) {
        int d = dst[i];
        int pos = atomicAdd(&cursor[d], 1);
        csr_src[pos] = src[i];
    }
}

// ---------------- prep: M1 = emb @ W1 (f32)  +  W2 bf16 fragment swizzle ----
__global__ void __launch_bounds__(256) prep_kernel(const float* __restrict__ emb,
                                                   const float* __restrict__ W1,
                                                   float* __restrict__ M1,
                                                   const float* __restrict__ W2,
                                                   unsigned short* __restrict__ Wb) {
    int b = blockIdx.x;
    if (b < 256) {
        int idx = b * 256 + threadIdx.x;   // 65536
        int v = idx >> 9, c = idx & 511;
        float acc = 0.f;
        for (int k = 0; k < 128; k++)
            acc += emb[v * 128 + k] * W1[k * 512 + c];
        M1[idx] = acc;
    } else {
        int idx = (b - 256) * 256 + threadIdx.x;   // 65536
        int j = idx & 7, c = (idx >> 3) & 511, qq = idx >> 12;
        Wb[idx] = f2b(W2[(qq * 8 + j) * 512 + c]);
    }
}

// ---------------- h1 = M1[feats] + b1 -> fp8 e4m3 ----------------
__global__ void gather_kernel(const int* __restrict__ feats, const float* __restrict__ M1,
                              const float* __restrict__ b1,
                              unsigned int* __restrict__ h) {
    int tid = blockIdx.x * blockDim.x + threadIdx.x;   // N*512/8
    int i0 = tid * 8;
    int n = i0 >> 9, c = i0 & 511;
    if (n >= N_NODES) return;
    int f = feats[n];
    const float* mrow = &M1[f * 512 + c];
    float v[8];
    #pragma unroll
    for (int j = 0; j < 8; j++) v[j] = mrow[j] + b1[c + j];
    uint2 o;
    o.x = __builtin_amdgcn_cvt_pk_fp8_f32(v[0], v[1], 0, false);
    o.x = __builtin_amdgcn_cvt_pk_fp8_f32(v[2], v[3], o.x, true);
    o.y = __builtin_amdgcn_cvt_pk_fp8_f32(v[4], v[5], 0, false);
    o.y = __builtin_amdgcn_cvt_pk_fp8_f32(v[6], v[7], o.y, true);
    *reinterpret_cast<uint2*>(&h[i0 >> 2]) = o;
}

// ---------------- GATv2 layer ----------------
// fp8 h, f16 packed math, DPP reduce, 4-deep prefetch, split logit chain.
// WRITE_DOTS: instead of storing x, emit dot(x_row, wreg) per node (layer 2).
template<bool WRITE_DOTS>
__global__ void __launch_bounds__(256) gat_kernel(const unsigned int* __restrict__ h,
                                                  const int* __restrict__ offsets,
                                                  const int* __restrict__ csr_src,
                                                  const float* __restrict__ a,
                                                  const float* __restrict__ wreg,
                                                  unsigned short* __restrict__ x,
                                                  float* __restrict__ dots) {
    int wid = threadIdx.x >> 6;
    int lane = threadIdx.x & 63;
    int n = blockIdx.x * 4 + wid;
    if (n >= N_NODES) return;
    int row_s = offsets[n], row_e = offsets[n + 1];
    int cnt = row_e - row_s;

    h16x2 hd2[4], a06[4], a04[4], acc2[4];
    float pd;
    {
        uint2 hv = *reinterpret_cast<const uint2*>(&h[(size_t)n * 128 + lane * 2]);
        fp8x4_to_h16(hv.x, hd2[0], hd2[1]);
        fp8x4_to_h16(hv.y, hd2[2], hd2[3]);
        float4 av0 = *reinterpret_cast<const float4*>(&a[lane * 8]);
        float4 av1 = *reinterpret_cast<const float4*>(&a[lane * 8 + 4]);
        float aa[8] = {av0.x, av0.y, av0.z, av0.w, av1.x, av1.y, av1.z, av1.w};
        const float L2E = 1.4426950408889634f;
        #pragma unroll
        for (int k = 0; k < 4; k++) {
            a06[k][0] = (_Float16)(aa[2*k]   * (0.6f * L2E));
            a06[k][1] = (_Float16)(aa[2*k+1] * (0.6f * L2E));
            a04[k][0] = (_Float16)(aa[2*k]   * (0.4f * L2E));
            a04[k][1] = (_Float16)(aa[2*k+1] * (0.4f * L2E));
            acc2[k][0] = (_Float16)0.f; acc2[k][1] = (_Float16)0.f;
        }
        float s = 0.f;
        #pragma unroll
        for (int k = 0; k < 4; k++) s = __builtin_amdgcn_fdot2(hd2[k], a06[k], s, false);
        pd = row16_sum(s);
    }

    float den = 0.f;
    const float C1 = 0.69314718f, C2 = 0.24022651f, C3 = 0.05550411f;

    auto ld = [&](int ii) {
        int s = csr_src[row_s + ii];
        return *reinterpret_cast<const uint2*>(&h[(size_t)s * 128 + lane * 2]);
    };

    auto process = [&](uint2 sv) {
        h16x2 hs[4];
        fp8x4_to_h16(sv.x, hs[0], hs[1]);
        fp8x4_to_h16(sv.y, hs[2], hs[3]);
        float p0 = 0.f, p1 = 0.f;          // two parallel chains (ILP)
        #pragma unroll
        for (int k = 0; k < 2; k++) {
            h16x2 t2 = hs[k] + hd2[k];
            h16x2 at2 = u2h2(h22u(t2) & 0x7FFF7FFFu);
            p0 = __builtin_amdgcn_fdot2(hs[k], a06[k], p0, false);
            p0 = __builtin_amdgcn_fdot2(at2, a04[k], p0, false);
        }
        #pragma unroll
        for (int k = 2; k < 4; k++) {
            h16x2 t2 = hs[k] + hd2[k];
            h16x2 at2 = u2h2(h22u(t2) & 0x7FFF7FFFu);
            p1 = __builtin_amdgcn_fdot2(hs[k], a06[k], p1, false);
            p1 = __builtin_amdgcn_fdot2(at2, a04[k], p1, false);
        }
        float p = row16_sum(p0 + p1) + pd;
        float w = fmaf(p, fmaf(p, fmaf(p, C3, C2), C1), 1.f);
        den += w;
        h16x2 w2 = packf2(w, w);
        #pragma unroll
        for (int k = 0; k < 4; k++) acc2[k] = w2 * hs[k] + acc2[k];
    };

    uint2 r0 = make_uint2(0, 0), r1 = r0, r2 = r0, r3 = r0;
    if (cnt > 0) {
        r0 = ld(0);
        r1 = ld(min(1, cnt - 1));
        r2 = ld(min(2, cnt - 1));
        r3 = ld(min(3, cnt - 1));
    }
    for (int i = 0; i < cnt; i += 4) {
        { uint2 cur = r0; if (i + 4 < cnt) r0 = ld(i + 4); process(cur); }
        if (i + 1 < cnt) { uint2 cur = r1; if (i + 5 < cnt) r1 = ld(i + 5); process(cur); }
        if (i + 2 < cnt) { uint2 cur = r2; if (i + 6 < cnt) r2 = ld(i + 6); process(cur); }
        if (i + 3 < cnt) { uint2 cur = r3; if (i + 7 < cnt) r3 = ld(i + 7); process(cur); }
    }

    float inv = (den > 0.f) ? 0.25f / den : 0.f;
    float out8[8];
    #pragma unroll
    for (int j = 0; j < 8; j++) {
        float r = (float)acc2[j >> 1][j & 1] * inv;
        r += __shfl_xor(r, 16);
        r += __shfl_xor(r, 32);
        out8[j] = r;
    }
    if constexpr (WRITE_DOTS) {
        int d0 = (lane & 15) * 8;
        float4 wv0 = *reinterpret_cast<const float4*>(&wreg[d0]);
        float4 wv1 = *reinterpret_cast<const float4*>(&wreg[d0 + 4]);
        float pdot = out8[0] * wv0.x + out8[1] * wv0.y + out8[2] * wv0.z + out8[3] * wv0.w
                   + out8[4] * wv1.x + out8[5] * wv1.y + out8[6] * wv1.z + out8[7] * wv1.w;
        pdot = row16_sum(pdot);
        if (lane == 0) dots[n] = pdot;
    } else {
        if (lane < 16) {
            union { unsigned short u[8]; uint4 v; } o;
            #pragma unroll
            for (int j = 0; j < 8; j++) o.u[j] = f2b(out8[j]);
            *reinterpret_cast<uint4*>(&x[(size_t)n * 128 + lane * 8]) = o.v;
        }
    }
}

// ---------------- h2 = x @ W2 + b2 via MFMA (swapped operands) ----------------
__global__ void __launch_bounds__(256) gemm_kernel(const unsigned short* __restrict__ x,
                                                   const unsigned short* __restrict__ Wb,
                                                   const float* __restrict__ bias,
                                                   unsigned char* __restrict__ hout) {
    int w = threadIdx.x >> 6, l = threadIdx.x & 63;
    int rb = blockIdx.x * 64 + w * 16;
    int cb = blockIdx.y * 64;
    int lr = l & 15, lq = l >> 4;
    f32x4 acc[4] = {};
    int arow = rb + lr;
    bool rok = arow < N_NODES;
    #pragma unroll
    for (int s = 0; s < 4; s++) {
        s16x8 afr = {};
        if (rok) afr = *reinterpret_cast<const s16x8*>(&x[(size_t)arow * 128 + s * 32 + lq * 8]);
        #pragma unroll
        for (int sub = 0; sub < 4; sub++) {
            s16x8 bfr = *reinterpret_cast<const s16x8*>(
                &Wb[(((size_t)(s * 4 + lq) * 512) + cb + sub * 16 + lr) << 3]);
            acc[sub] = __builtin_amdgcn_mfma_f32_16x16x32_bf16(bfr, afr, acc[sub], 0, 0, 0);
        }
    }
    if (!rok) return;
    #pragma unroll
    for (int sub = 0; sub < 4; sub++) {
        int col0 = cb + sub * 16 + lq * 4;
        float4 bb = *reinterpret_cast<const float4*>(&bias[col0]);
        unsigned int pk = __builtin_amdgcn_cvt_pk_fp8_f32(acc[sub][0] + bb.x,
                                                          acc[sub][1] + bb.y, 0, false);
        pk = __builtin_amdgcn_cvt_pk_fp8_f32(acc[sub][2] + bb.z,
                                             acc[sub][3] + bb.w, pk, true);
        *reinterpret_cast<unsigned int*>(&hout[(size_t)arow * 512 + col0]) = pk;
    }
}

// ---------------- pool over per-node dots (gids sorted) ----------------
__global__ void __launch_bounds__(256) pool64_kernel(const float* __restrict__ dots,
                                                     const int* __restrict__ gid,
                                                     float* __restrict__ pool) {
    int wave = (blockIdx.x * blockDim.x + threadIdx.x) >> 6;
    int lane = threadIdx.x & 63;
    int n0 = wave * 64;
    if (n0 >= N_NODES) return;
    int n = n0 + lane;
    int nc = min(n, N_NODES - 1);
    int g = gid[nc];
    float v = (n < N_NODES) ? dots[n] : 0.f;
    int g0 = __shfl(g, 0);
    bool uni = __all(g == g0);
    if (uni) {
        v += __shfl_xor(v, 1);
        v += __shfl_xor(v, 2);
        v += __shfl_xor(v, 4);
        v += __shfl_xor(v, 8);
        v += __shfl_xor(v, 16);
        v += __shfl_xor(v, 32);
        if (lane == 0) atomicAdd(&pool[g0], v);
    } else {
        if (n < N_NODES) atomicAdd(&pool[g], v);   // rare boundary wave
    }
}

__global__ void final_kernel(const float* __restrict__ pool, float* __restrict__ out) {
    int t = threadIdx.x;
    if (t < G_GRAPHS) out[t] = pool[t];
}

extern "C" void kernel_launch(void* const* d_in, const int* in_sizes, int n_in,
                              void* d_out, int out_size, void* d_ws, size_t ws_size,
                              hipStream_t stream) {
    const int* feats = (const int*)d_in[0];
    const int* src   = (const int*)d_in[1];
    const int* dst   = (const int*)d_in[2];
    const int* gids  = (const int*)d_in[3];
    const float* emb  = (const float*)d_in[4];
    const float* W1   = (const float*)d_in[5];
    const float* b1   = (const float*)d_in[6];
    const float* a1   = (const float*)d_in[7];
    const float* W2   = (const float*)d_in[8];
    const float* b2   = (const float*)d_in[9];
    const float* a2   = (const float*)d_in[10];
    const float* wreg = (const float*)d_in[11];
    float* out = (float*)d_out;

    char* ws = (char*)d_ws;
    size_t off = 0;
    auto alloc = [&](size_t bytes) -> void* {
        void* p = ws + off;
        off = (off + bytes + 255) & ~(size_t)255;
        return p;
    };
    int*   counts  = (int*)alloc((size_t)N_NODES * 4);
    int*   offsets = (int*)alloc((size_t)(N_NODES + 1) * 4);
    int*   cursor  = (int*)alloc((size_t)N_NODES * 4);
    int*   csr_src = (int*)alloc((size_t)N_EDGES * 4);
    int*   bsum    = (int*)alloc(64 * 4);
    float* M1      = (float*)alloc((size_t)V_VOCAB * HD * 4);
    unsigned int*   h  = (unsigned int*)alloc((size_t)N_NODES * HD);      // fp8
    unsigned short* x  = (unsigned short*)alloc((size_t)N_NODES * D_DIM * 2);
    unsigned short* Wb = (unsigned short*)alloc((size_t)D_DIM * HD * 2);
    float* dots    = (float*)alloc((size_t)N_NODES * 4);
    float* pool    = (float*)alloc((size_t)G_GRAPHS * 4);

    hipMemsetAsync(counts, 0, (size_t)N_NODES * 4, stream);

    hist_kernel<<<(N_EDGES + 255) / 256, 256, 0, stream>>>(dst, counts, pool);
    scan1_kernel<<<64, 256, 0, stream>>>(counts, offsets, bsum);
    scan23_kernel<<<64, 256, 0, stream>>>(counts, offsets, bsum, cursor);
    scatter_kernel<<<(N_EDGES + 255) / 256, 256, 0, stream>>>(src, dst, cursor, csr_src);

    prep_kernel<<<512, 256, 0, stream>>>(emb, W1, M1, W2, Wb);
    gather_kernel<<<(N_NODES * HD / 8) / 256, 256, 0, stream>>>(feats, M1, b1, h);

    gat_kernel<false><<<(N_NODES + 3) / 4, 256, 0, stream>>>(h, offsets, csr_src, a1,
                                                             wreg, x, dots);
    gemm_kernel<<<dim3((N_NODES + 63) / 64, 8), 256, 0, stream>>>(x, Wb, b2, (unsigned char*)h);
    gat_kernel<true><<<(N_NODES + 3) / 4, 256, 0, stream>>>(h, offsets, csr_src, a2,
                                                            wreg, x, dots);

    pool64_kernel<<<(N_NODES / 64 + 4) / 4, 256, 0, stream>>>(dots, gids, pool);
    final_kernel<<<1, 64, 0, stream>>>(pool, out);
}

// Round 14
// 362.915 us; speedup vs baseline: 1.0100x; 1.0100x over previous
//
#include <hip/hip_runtime.h>
#include <hip/hip_bf16.h>

#define N_NODES 50000
#define N_EDGES 800000
#define G_GRAPHS 64
#define H_HEADS 4
#define D_DIM 128
#define HD 512
#define V_VOCAB 128
#define NEG_SLOPE 0.2f

typedef float f32x2v __attribute__((ext_vector_type(2)));
typedef float f32x4 __attribute__((ext_vector_type(4)));
typedef short s16x8 __attribute__((ext_vector_type(8)));
typedef _Float16 h16x2 __attribute__((ext_vector_type(2)));

static __device__ __forceinline__ float blo(unsigned int u) {
    union { float f; unsigned int i; } x; x.i = u << 16; return x.f;
}
static __device__ __forceinline__ float bhi(unsigned int u) {
    union { float f; unsigned int i; } x; x.i = u & 0xffff0000u; return x.f;
}
static __device__ __forceinline__ unsigned short f2b(float f) {
    union { float f; unsigned int i; } x; x.f = f;
    unsigned int r = x.i + 0x7fffu + ((x.i >> 16) & 1u);
    return (unsigned short)(r >> 16);
}
static __device__ __forceinline__ h16x2 u2h2(unsigned int u) {
    union { unsigned int u; h16x2 h; } c; c.u = u; return c.h;
}
static __device__ __forceinline__ unsigned int h22u(h16x2 h) {
    union { unsigned int u; h16x2 h; } c; c.h = h; return c.u;
}
static __device__ __forceinline__ h16x2 packf2(float lo, float hi) {
    union { __fp16 __attribute__((ext_vector_type(2))) p; h16x2 h; } c;
    c.p = __builtin_amdgcn_cvt_pkrtz(lo, hi);
    return c.h;
}

// unpack 4 fp8 (one dword) -> 2 h16x2
#if __has_builtin(__builtin_amdgcn_cvt_scalef32_pk_f16_fp8)
static __device__ __forceinline__ void fp8x4_to_h16(unsigned int u, h16x2& h0, h16x2& h1) {
    auto r0 = __builtin_amdgcn_cvt_scalef32_pk_f16_fp8((int)u, 1.0f, false);
    auto r1 = __builtin_amdgcn_cvt_scalef32_pk_f16_fp8((int)u, 1.0f, true);
    union { decltype(r0) p; h16x2 h; } c0, c1;
    c0.p = r0; c1.p = r1;
    h0 = c0.h; h1 = c1.h;
}
#else
static __device__ __forceinline__ void fp8x4_to_h16(unsigned int u, h16x2& h0, h16x2& h1) {
    f32x2v lo = __builtin_amdgcn_cvt_pk_f32_fp8(u, false);
    f32x2v hi = __builtin_amdgcn_cvt_pk_f32_fp8(u, true);
    h0 = packf2(lo.x, lo.y);
    h1 = packf2(hi.x, hi.y);
}
#endif

// butterfly-add over the 16-lane row via DPP (VALU pipe, no LDS latency)
template<int CTRL>
static __device__ __forceinline__ float dpp_add(float v) {
    union { float f; int i; } a, b;
    a.f = v;
    b.i = __builtin_amdgcn_mov_dpp(a.i, CTRL, 0xF, 0xF, true);
    return v + b.f;
}
static __device__ __forceinline__ float row16_sum(float p) {
    p = dpp_add<0xB1>(p);    // quad_perm [1,0,3,2]  : xor 1
    p = dpp_add<0x4E>(p);    // quad_perm [2,3,0,1]  : xor 2
    p = dpp_add<0x141>(p);   // ROW_HALF_MIRROR      : cross-quad in 8
    p = dpp_add<0x140>(p);   // ROW_MIRROR           : cross-8 in 16
    return p;
}

// ---------------- CSR build ----------------
__global__ void hist_kernel(const int* __restrict__ dst, int* __restrict__ counts,
                            float* __restrict__ pool) {
    if (blockIdx.x == 0 && threadIdx.x < G_GRAPHS) pool[threadIdx.x] = 0.f;
    int i = blockIdx.x * blockDim.x + threadIdx.x;
    if (i < N_EDGES) atomicAdd(&counts[dst[i]], 1);
}

__global__ void __launch_bounds__(256) scan1_kernel(const int* __restrict__ counts,
                                                    int* __restrict__ offsets,
                                                    int* __restrict__ bsum) {
    __shared__ int buf[256];
    int t = threadIdx.x, b = blockIdx.x;
    int i0 = (b * 256 + t) * 4;
    int v[4], c[4], s = 0;
    #pragma unroll
    for (int j = 0; j < 4; j++) {
        int idx = i0 + j;
        v[j] = (idx < N_NODES) ? counts[idx] : 0;
        s += v[j];
        c[j] = s;
    }
    buf[t] = s;
    __syncthreads();
    for (int off = 1; off < 256; off <<= 1) {
        int add = (t >= off) ? buf[t - off] : 0;
        __syncthreads();
        buf[t] += add;
        __syncthreads();
    }
    int ebase = (t > 0) ? buf[t - 1] : 0;
    #pragma unroll
    for (int j = 0; j < 4; j++) {
        int idx = i0 + j;
        if (idx < N_NODES) offsets[idx + 1] = ebase + c[j];
    }
    if (t == 0) bsum[b] = buf[255];
}

__global__ void __launch_bounds__(256) scan23_kernel(const int* __restrict__ counts,
                                                     int* __restrict__ offsets,
                                                     const int* __restrict__ bsum,
                                                     int* __restrict__ cursor) {
    __shared__ int sbase;
    int t = threadIdx.x, b = blockIdx.x;
    if (t < 64) {
        int v = (t < b) ? bsum[t] : 0;
        #pragma unroll
        for (int off = 1; off < 64; off <<= 1) v += __shfl_xor(v, off);
        if (t == 0) sbase = v;
    }
    __syncthreads();
    int base = sbase;
    int i0 = (b * 256 + t) * 4;
    #pragma unroll
    for (int j = 0; j < 4; j++) {
        int idx = i0 + j;
        if (idx < N_NODES) {
            int e = offsets[idx + 1] + base;
            offsets[idx + 1] = e;
            cursor[idx] = e - counts[idx];
        }
    }
    if (b == 0 && t == 0) offsets[0] = 0;
}

__global__ void scatter_kernel(const int* __restrict__ src, const int* __restrict__ dst,
                               int* __restrict__ cursor, int* __restrict__ csr_src) {
    int i = blockIdx.x * blockDim.x + threadIdx.x;
    if (i < N_EDGES) {
        int d = dst[i];
        int pos = atomicAdd(&cursor[d], 1);
        csr_src[pos] = src[i];
    }
}

// ---------------- prep: M1 = emb @ W1 (f32)  +  W2 bf16 fragment swizzle ----
__global__ void __launch_bounds__(256) prep_kernel(const float* __restrict__ emb,
                                                   const float* __restrict__ W1,
                                                   float* __restrict__ M1,
                                                   const float* __restrict__ W2,
                                                   unsigned short* __restrict__ Wb) {
    int b = blockIdx.x;
    if (b < 256) {
        int idx = b * 256 + threadIdx.x;   // 65536
        int v = idx >> 9, c = idx & 511;
        float acc = 0.f;
        for (int k = 0; k < 128; k++)
            acc += emb[v * 128 + k] * W1[k * 512 + c];
        M1[idx] = acc;
    } else {
        int idx = (b - 256) * 256 + threadIdx.x;   // 65536
        int j = idx & 7, c = (idx >> 3) & 511, qq = idx >> 12;
        Wb[idx] = f2b(W2[(qq * 8 + j) * 512 + c]);
    }
}

// ---------------- h1 = M1[feats] + b1 -> fp8 e4m3 ----------------
__global__ void gather_kernel(const int* __restrict__ feats, const float* __restrict__ M1,
                              const float* __restrict__ b1,
                              unsigned int* __restrict__ h) {
    int tid = blockIdx.x * blockDim.x + threadIdx.x;   // N*512/8
    int i0 = tid * 8;
    int n = i0 >> 9, c = i0 & 511;
    if (n >= N_NODES) return;
    int f = feats[n];
    const float* mrow = &M1[f * 512 + c];
    float v[8];
    #pragma unroll
    for (int j = 0; j < 8; j++) v[j] = mrow[j] + b1[c + j];
    uint2 o;
    o.x = __builtin_amdgcn_cvt_pk_fp8_f32(v[0], v[1], 0, false);
    o.x = __builtin_amdgcn_cvt_pk_fp8_f32(v[2], v[3], o.x, true);
    o.y = __builtin_amdgcn_cvt_pk_fp8_f32(v[4], v[5], 0, false);
    o.y = __builtin_amdgcn_cvt_pk_fp8_f32(v[6], v[7], o.y, true);
    *reinterpret_cast<uint2*>(&h[i0 >> 2]) = o;
}

// ---------------- GATv2 layer ----------------
// fp8 h, f16 packed math, DPP reduce, 2-deep branchless prefetch (round-12
// structure -- 4-deep regressed, VALU-issue-bound), split p0/p1 chains.
// WRITE_DOTS: emit dot(x_row, wreg) per node instead of storing x (layer 2).
template<bool WRITE_DOTS>
__global__ void __launch_bounds__(256) gat_kernel(const unsigned int* __restrict__ h,
                                                  const int* __restrict__ offsets,
                                                  const int* __restrict__ csr_src,
                                                  const float* __restrict__ a,
                                                  const float* __restrict__ wreg,
                                                  unsigned short* __restrict__ x,
                                                  float* __restrict__ dots) {
    int wid = threadIdx.x >> 6;
    int lane = threadIdx.x & 63;
    int n = blockIdx.x * 4 + wid;
    if (n >= N_NODES) return;
    int row_s = offsets[n], row_e = offsets[n + 1];
    int cnt = row_e - row_s;

    h16x2 hd2[4], a06[4], a04[4], acc2[4];
    float pd;
    {
        uint2 hv = *reinterpret_cast<const uint2*>(&h[(size_t)n * 128 + lane * 2]);
        fp8x4_to_h16(hv.x, hd2[0], hd2[1]);
        fp8x4_to_h16(hv.y, hd2[2], hd2[3]);
        float4 av0 = *reinterpret_cast<const float4*>(&a[lane * 8]);
        float4 av1 = *reinterpret_cast<const float4*>(&a[lane * 8 + 4]);
        float aa[8] = {av0.x, av0.y, av0.z, av0.w, av1.x, av1.y, av1.z, av1.w};
        const float L2E = 1.4426950408889634f;
        #pragma unroll
        for (int k = 0; k < 4; k++) {
            a06[k][0] = (_Float16)(aa[2*k]   * (0.6f * L2E));
            a06[k][1] = (_Float16)(aa[2*k+1] * (0.6f * L2E));
            a04[k][0] = (_Float16)(aa[2*k]   * (0.4f * L2E));
            a04[k][1] = (_Float16)(aa[2*k+1] * (0.4f * L2E));
            acc2[k][0] = (_Float16)0.f; acc2[k][1] = (_Float16)0.f;
        }
        float s = 0.f;
        #pragma unroll
        for (int k = 0; k < 4; k++) s = __builtin_amdgcn_fdot2(hd2[k], a06[k], s, false);
        pd = row16_sum(s);
    }

    float den = 0.f;
    uint2 rA = make_uint2(0, 0), rB = make_uint2(0, 0);
    if (cnt > 0) {
        int s = csr_src[row_s];
        rA = *reinterpret_cast<const uint2*>(&h[(size_t)s * 128 + lane * 2]);
    }
    if (cnt > 1) {
        int s = csr_src[row_s + 1];
        rB = *reinterpret_cast<const uint2*>(&h[(size_t)s * 128 + lane * 2]);
    }

    const float C1 = 0.69314718f, C2 = 0.24022651f, C3 = 0.05550411f;

    auto process = [&](uint2 sv) {
        h16x2 hs[4];
        fp8x4_to_h16(sv.x, hs[0], hs[1]);
        fp8x4_to_h16(sv.y, hs[2], hs[3]);
        float p0 = 0.f, p1 = 0.f;          // two parallel chains (ILP)
        #pragma unroll
        for (int k = 0; k < 2; k++) {
            h16x2 t2 = hs[k] + hd2[k];
            h16x2 at2 = u2h2(h22u(t2) & 0x7FFF7FFFu);
            p0 = __builtin_amdgcn_fdot2(hs[k], a06[k], p0, false);
            p0 = __builtin_amdgcn_fdot2(at2, a04[k], p0, false);
        }
        #pragma unroll
        for (int k = 2; k < 4; k++) {
            h16x2 t2 = hs[k] + hd2[k];
            h16x2 at2 = u2h2(h22u(t2) & 0x7FFF7FFFu);
            p1 = __builtin_amdgcn_fdot2(hs[k], a06[k], p1, false);
            p1 = __builtin_amdgcn_fdot2(at2, a04[k], p1, false);
        }
        float p = row16_sum(p0 + p1) + pd;
        float w = fmaf(p, fmaf(p, fmaf(p, C3, C2), C1), 1.f);
        den += w;
        h16x2 w2 = packf2(w, w);
        #pragma unroll
        for (int k = 0; k < 4; k++) acc2[k] = w2 * hs[k] + acc2[k];
    };

    for (int i = 0; i < cnt; i += 2) {
        {
            uint2 cur = rA;
            int nx = min(i + 2, cnt - 1);
            int s = csr_src[row_s + nx];
            rA = *reinterpret_cast<const uint2*>(&h[(size_t)s * 128 + lane * 2]);
            process(cur);
        }
        if (i + 1 < cnt) {
            uint2 cur = rB;
            int nx = min(i + 3, cnt - 1);
            int s = csr_src[row_s + nx];
            rB = *reinterpret_cast<const uint2*>(&h[(size_t)s * 128 + lane * 2]);
            process(cur);
        }
    }

    float inv = (den > 0.f) ? 0.25f / den : 0.f;
    float out8[8];
    #pragma unroll
    for (int j = 0; j < 8; j++) {
        float r = (float)acc2[j >> 1][j & 1] * inv;
        r += __shfl_xor(r, 16);
        r += __shfl_xor(r, 32);
        out8[j] = r;
    }
    if constexpr (WRITE_DOTS) {
        int d0 = (lane & 15) * 8;
        float4 wv0 = *reinterpret_cast<const float4*>(&wreg[d0]);
        float4 wv1 = *reinterpret_cast<const float4*>(&wreg[d0 + 4]);
        float pdot = out8[0] * wv0.x + out8[1] * wv0.y + out8[2] * wv0.z + out8[3] * wv0.w
                   + out8[4] * wv1.x + out8[5] * wv1.y + out8[6] * wv1.z + out8[7] * wv1.w;
        pdot = row16_sum(pdot);
        if (lane == 0) dots[n] = pdot;
    } else {
        if (lane < 16) {
            union { unsigned short u[8]; uint4 v; } o;
            #pragma unroll
            for (int j = 0; j < 8; j++) o.u[j] = f2b(out8[j]);
            *reinterpret_cast<uint4*>(&x[(size_t)n * 128 + lane * 8]) = o.v;
        }
    }
}

// ---------------- h2 = x @ W2 + b2 via MFMA (swapped operands) ----------------
__global__ void __launch_bounds__(256) gemm_kernel(const unsigned short* __restrict__ x,
                                                   const unsigned short* __restrict__ Wb,
                                                   const float* __restrict__ bias,
                                                   unsigned char* __restrict__ hout) {
    int w = threadIdx.x >> 6, l = threadIdx.x & 63;
    int rb = blockIdx.x * 64 + w * 16;
    int cb = blockIdx.y * 64;
    int lr = l & 15, lq = l >> 4;
    f32x4 acc[4] = {};
    int arow = rb + lr;
    bool rok = arow < N_NODES;
    #pragma unroll
    for (int s = 0; s < 4; s++) {
        s16x8 afr = {};
        if (rok) afr = *reinterpret_cast<const s16x8*>(&x[(size_t)arow * 128 + s * 32 + lq * 8]);
        #pragma unroll
        for (int sub = 0; sub < 4; sub++) {
            s16x8 bfr = *reinterpret_cast<const s16x8*>(
                &Wb[(((size_t)(s * 4 + lq) * 512) + cb + sub * 16 + lr) << 3]);
            acc[sub] = __builtin_amdgcn_mfma_f32_16x16x32_bf16(bfr, afr, acc[sub], 0, 0, 0);
        }
    }
    if (!rok) return;
    #pragma unroll
    for (int sub = 0; sub < 4; sub++) {
        int col0 = cb + sub * 16 + lq * 4;
        float4 bb = *reinterpret_cast<const float4*>(&bias[col0]);
        unsigned int pk = __builtin_amdgcn_cvt_pk_fp8_f32(acc[sub][0] + bb.x,
                                                          acc[sub][1] + bb.y, 0, false);
        pk = __builtin_amdgcn_cvt_pk_fp8_f32(acc[sub][2] + bb.z,
                                             acc[sub][3] + bb.w, pk, true);
        *reinterpret_cast<unsigned int*>(&hout[(size_t)arow * 512 + col0]) = pk;
    }
}

// ---------------- pool over per-node dots (gids sorted) ----------------
__global__ void __launch_bounds__(256) pool64_kernel(const float* __restrict__ dots,
                                                     const int* __restrict__ gid,
                                                     float* __restrict__ pool) {
    int wave = (blockIdx.x * blockDim.x + threadIdx.x) >> 6;
    int lane = threadIdx.x & 63;
    int n0 = wave * 64;
    if (n0 >= N_NODES) return;
    int n = n0 + lane;
    int nc = min(n, N_NODES - 1);
    int g = gid[nc];
    float v = (n < N_NODES) ? dots[n] : 0.f;
    int g0 = __shfl(g, 0);
    bool uni = __all(g == g0);
    if (uni) {
        v += __shfl_xor(v, 1);
        v += __shfl_xor(v, 2);
        v += __shfl_xor(v, 4);
        v += __shfl_xor(v, 8);
        v += __shfl_xor(v, 16);
        v += __shfl_xor(v, 32);
        if (lane == 0) atomicAdd(&pool[g0], v);
    } else {
        if (n < N_NODES) atomicAdd(&pool[g], v);   // rare boundary wave
    }
}

__global__ void final_kernel(const float* __restrict__ pool, float* __restrict__ out) {
    int t = threadIdx.x;
    if (t < G_GRAPHS) out[t] = pool[t];
}

extern "C" void kernel_launch(void* const* d_in, const int* in_sizes, int n_in,
                              void* d_out, int out_size, void* d_ws, size_t ws_size,
                              hipStream_t stream) {
    const int* feats = (const int*)d_in[0];
    const int* src   = (const int*)d_in[1];
    const int* dst   = (const int*)d_in[2];
    const int* gids  = (const int*)d_in[3];
    const float* emb  = (const float*)d_in[4];
    const float* W1   = (const float*)d_in[5];
    const float* b1   = (const float*)d_in[6];
    const float* a1   = (const float*)d_in[7];
    const float* W2   = (const float*)d_in[8];
    const float* b2   = (const float*)d_in[9];
    const float* a2   = (const float*)d_in[10];
    const float* wreg = (const float*)d_in[11];
    float* out = (float*)d_out;

    char* ws = (char*)d_ws;
    size_t off = 0;
    auto alloc = [&](size_t bytes) -> void* {
        void* p = ws + off;
        off = (off + bytes + 255) & ~(size_t)255;
        return p;
    };
    int*   counts  = (int*)alloc((size_t)N_NODES * 4);
    int*   offsets = (int*)alloc((size_t)(N_NODES + 1) * 4);
    int*   cursor  = (int*)alloc((size_t)N_NODES * 4);
    int*   csr_src = (int*)alloc((size_t)N_EDGES * 4);
    int*   bsum    = (int*)alloc(64 * 4);
    float* M1      = (float*)alloc((size_t)V_VOCAB * HD * 4);
    unsigned int*   h  = (unsigned int*)alloc((size_t)N_NODES * HD);      // fp8
    unsigned short* x  = (unsigned short*)alloc((size_t)N_NODES * D_DIM * 2);
    unsigned short* Wb = (unsigned short*)alloc((size_t)D_DIM * HD * 2);
    float* dots    = (float*)alloc((size_t)N_NODES * 4);
    float* pool    = (float*)alloc((size_t)G_GRAPHS * 4);

    hipMemsetAsync(counts, 0, (size_t)N_NODES * 4, stream);

    hist_kernel<<<(N_EDGES + 255) / 256, 256, 0, stream>>>(dst, counts, pool);
    scan1_kernel<<<64, 256, 0, stream>>>(counts, offsets, bsum);
    scan23_kernel<<<64, 256, 0, stream>>>(counts, offsets, bsum, cursor);
    scatter_kernel<<<(N_EDGES + 255) / 256, 256, 0, stream>>>(src, dst, cursor, csr_src);

    prep_kernel<<<512, 256, 0, stream>>>(emb, W1, M1, W2, Wb);
    gather_kernel<<<(N_NODES * HD / 8) / 256, 256, 0, stream>>>(feats, M1, b1, h);

    gat_kernel<false><<<(N_NODES + 3) / 4, 256, 0, stream>>>(h, offsets, csr_src, a1,
                                                             wreg, x, dots);
    gemm_kernel<<<dim3((N_NODES + 63) / 64, 8), 256, 0, stream>>>(x, Wb, b2, (unsigned char*)h);
    gat_kernel<true><<<(N_NODES + 3) / 4, 256, 0, stream>>>(h, offsets, csr_src, a2,
                                                            wreg, x, dots);

    pool64_kernel<<<(N_NODES / 64 + 4) / 4, 256, 0, stream>>>(dots, gids, pool);
    final_kernel<<<1, 64, 0, stream>>>(pool, out);
}

// Round 15
// 335.184 us; speedup vs baseline: 1.0936x; 1.0827x over previous
//
#include <hip/hip_runtime.h>
#include <hip/hip_bf16.h>

#define N_NODES 50000
#define N_EDGES 800000
#define G_GRAPHS 64
#define H_HEADS 4
#define D_DIM 128
#define HD 512
#define V_VOCAB 128
#define NEG_SLOPE 0.2f

typedef float f32x2v __attribute__((ext_vector_type(2)));
typedef float f32x4 __attribute__((ext_vector_type(4)));
typedef short s16x8 __attribute__((ext_vector_type(8)));
typedef _Float16 h16x2 __attribute__((ext_vector_type(2)));

static __device__ __forceinline__ unsigned short f2b(float f) {
    union { float f; unsigned int i; } x; x.f = f;
    unsigned int r = x.i + 0x7fffu + ((x.i >> 16) & 1u);
    return (unsigned short)(r >> 16);
}
static __device__ __forceinline__ h16x2 u2h2(unsigned int u) {
    union { unsigned int u; h16x2 h; } c; c.u = u; return c.h;
}
static __device__ __forceinline__ unsigned int h22u(h16x2 h) {
    union { unsigned int u; h16x2 h; } c; c.h = h; return c.u;
}
static __device__ __forceinline__ h16x2 packf2(float lo, float hi) {
    union { __fp16 __attribute__((ext_vector_type(2))) p; h16x2 h; } c;
    c.p = __builtin_amdgcn_cvt_pkrtz(lo, hi);
    return c.h;
}

// unpack 4 fp8 (one dword) -> 2 h16x2
#if __has_builtin(__builtin_amdgcn_cvt_scalef32_pk_f16_fp8)
static __device__ __forceinline__ void fp8x4_to_h16(unsigned int u, h16x2& h0, h16x2& h1) {
    auto r0 = __builtin_amdgcn_cvt_scalef32_pk_f16_fp8((int)u, 1.0f, false);
    auto r1 = __builtin_amdgcn_cvt_scalef32_pk_f16_fp8((int)u, 1.0f, true);
    union { decltype(r0) p; h16x2 h; } c0, c1;
    c0.p = r0; c1.p = r1;
    h0 = c0.h; h1 = c1.h;
}
#else
static __device__ __forceinline__ void fp8x4_to_h16(unsigned int u, h16x2& h0, h16x2& h1) {
    f32x2v lo = __builtin_amdgcn_cvt_pk_f32_fp8(u, false);
    f32x2v hi = __builtin_amdgcn_cvt_pk_f32_fp8(u, true);
    h0 = packf2(lo.x, lo.y);
    h1 = packf2(hi.x, hi.y);
}
#endif

// butterfly-add over the 16-lane row via DPP (VALU pipe, no LDS latency)
template<int CTRL>
static __device__ __forceinline__ float dpp_add(float v) {
    union { float f; int i; } a, b;
    a.f = v;
    b.i = __builtin_amdgcn_mov_dpp(a.i, CTRL, 0xF, 0xF, true);
    return v + b.f;
}
static __device__ __forceinline__ float row16_sum(float p) {
    p = dpp_add<0xB1>(p);    // quad_perm [1,0,3,2]  : xor 1
    p = dpp_add<0x4E>(p);    // quad_perm [2,3,0,1]  : xor 2
    p = dpp_add<0x141>(p);   // ROW_HALF_MIRROR      : cross-quad in 8
    p = dpp_add<0x140>(p);   // ROW_MIRROR           : cross-8 in 16
    return p;
}

// ---------------- CSR build ----------------
__global__ void hist_kernel(const int* __restrict__ dst, int* __restrict__ counts,
                            float* __restrict__ pool) {
    if (blockIdx.x == 0 && threadIdx.x < G_GRAPHS) pool[threadIdx.x] = 0.f;
    int i = blockIdx.x * blockDim.x + threadIdx.x;
    if (i < N_EDGES) atomicAdd(&counts[dst[i]], 1);
}

__global__ void __launch_bounds__(256) scan1_kernel(const int* __restrict__ counts,
                                                    int* __restrict__ offsets,
                                                    int* __restrict__ bsum) {
    __shared__ int buf[256];
    int t = threadIdx.x, b = blockIdx.x;
    int i0 = (b * 256 + t) * 4;
    int v[4], c[4], s = 0;
    #pragma unroll
    for (int j = 0; j < 4; j++) {
        int idx = i0 + j;
        v[j] = (idx < N_NODES) ? counts[idx] : 0;
        s += v[j];
        c[j] = s;
    }
    buf[t] = s;
    __syncthreads();
    for (int off = 1; off < 256; off <<= 1) {
        int add = (t >= off) ? buf[t - off] : 0;
        __syncthreads();
        buf[t] += add;
        __syncthreads();
    }
    int ebase = (t > 0) ? buf[t - 1] : 0;
    #pragma unroll
    for (int j = 0; j < 4; j++) {
        int idx = i0 + j;
        if (idx < N_NODES) offsets[idx + 1] = ebase + c[j];
    }
    if (t == 0) bsum[b] = buf[255];
}

__global__ void __launch_bounds__(256) scan23_kernel(const int* __restrict__ counts,
                                                     int* __restrict__ offsets,
                                                     const int* __restrict__ bsum,
                                                     int* __restrict__ cursor) {
    __shared__ int sbase;
    int t = threadIdx.x, b = blockIdx.x;
    if (t < 64) {
        int v = (t < b) ? bsum[t] : 0;
        #pragma unroll
        for (int off = 1; off < 64; off <<= 1) v += __shfl_xor(v, off);
        if (t == 0) sbase = v;
    }
    __syncthreads();
    int base = sbase;
    int i0 = (b * 256 + t) * 4;
    #pragma unroll
    for (int j = 0; j < 4; j++) {
        int idx = i0 + j;
        if (idx < N_NODES) {
            int e = offsets[idx + 1] + base;
            offsets[idx + 1] = e;
            cursor[idx] = e - counts[idx];
        }
    }
    if (b == 0 && t == 0) offsets[0] = 0;
}

__global__ void scatter_kernel(const int* __restrict__ src, const int* __restrict__ dst,
                               int* __restrict__ cursor, int* __restrict__ csr_src) {
    int i = blockIdx.x * blockDim.x + threadIdx.x;
    if (i < N_EDGES) {
        int d = dst[i];
        int pos = atomicAdd(&cursor[d], 1);
        csr_src[pos] = src[i];
    }
}

// ---------------- prep: M1 = emb@W1 + W2 swizzle + zero counts/done ----------
#define PREP_M1_BLOCKS   256
#define PREP_WSZ_BLOCKS  256
#define PREP_CNT_BLOCKS  196
__global__ void __launch_bounds__(256) prep_kernel(const float* __restrict__ emb,
                                                   const float* __restrict__ W1,
                                                   float* __restrict__ M1,
                                                   const float* __restrict__ W2,
                                                   unsigned short* __restrict__ Wb,
                                                   int* __restrict__ counts,
                                                   int* __restrict__ done) {
    int b = blockIdx.x;
    if (b < PREP_M1_BLOCKS) {
        int idx = b * 256 + threadIdx.x;   // 65536
        int v = idx >> 9, c = idx & 511;
        float acc = 0.f;
        for (int k = 0; k < 128; k++)
            acc += emb[v * 128 + k] * W1[k * 512 + c];
        M1[idx] = acc;
    } else if (b < PREP_M1_BLOCKS + PREP_WSZ_BLOCKS) {
        int idx = (b - PREP_M1_BLOCKS) * 256 + threadIdx.x;   // 65536
        int j = idx & 7, c = (idx >> 3) & 511, qq = idx >> 12;
        Wb[idx] = f2b(W2[(qq * 8 + j) * 512 + c]);
    } else {
        int idx = (b - PREP_M1_BLOCKS - PREP_WSZ_BLOCKS) * 256 + threadIdx.x;
        if (idx < N_NODES) counts[idx] = 0;
        if (idx == 0) *done = 0;
    }
}

// ---------------- h1 = M1[feats] + b1 -> fp8 e4m3 ----------------
__global__ void gather_kernel(const int* __restrict__ feats, const float* __restrict__ M1,
                              const float* __restrict__ b1,
                              unsigned int* __restrict__ h) {
    int tid = blockIdx.x * blockDim.x + threadIdx.x;   // N*512/8
    int i0 = tid * 8;
    int n = i0 >> 9, c = i0 & 511;
    if (n >= N_NODES) return;
    int f = feats[n];
    const float* mrow = &M1[f * 512 + c];
    float v[8];
    #pragma unroll
    for (int j = 0; j < 8; j++) v[j] = mrow[j] + b1[c + j];
    uint2 o;
    o.x = __builtin_amdgcn_cvt_pk_fp8_f32(v[0], v[1], 0, false);
    o.x = __builtin_amdgcn_cvt_pk_fp8_f32(v[2], v[3], o.x, true);
    o.y = __builtin_amdgcn_cvt_pk_fp8_f32(v[4], v[5], 0, false);
    o.y = __builtin_amdgcn_cvt_pk_fp8_f32(v[6], v[7], o.y, true);
    *reinterpret_cast<uint2*>(&h[i0 >> 2]) = o;
}

// ---------------- GATv2 layer ----------------
// fp8 h, f16 packed math, DPP reduce, 2-deep branchless prefetch.
// SCALARIZED addressing: n/row_s/cnt/s forced to SGPRs via readfirstlane so
// csr_src reads become s_load (scalar pipe) and h-row loads use saddr form.
template<bool WRITE_DOTS>
__global__ void __launch_bounds__(256) gat_kernel(const unsigned int* __restrict__ h,
                                                  const int* __restrict__ offsets,
                                                  const int* __restrict__ csr_src,
                                                  const float* __restrict__ a,
                                                  const float* __restrict__ wreg,
                                                  unsigned short* __restrict__ x,
                                                  float* __restrict__ dots) {
    int wid = threadIdx.x >> 6;
    int lane = threadIdx.x & 63;
    int n = blockIdx.x * 4 + wid;
    if (n >= N_NODES) return;
    n = __builtin_amdgcn_readfirstlane(n);
    int row_s = __builtin_amdgcn_readfirstlane(offsets[n]);
    int row_e = __builtin_amdgcn_readfirstlane(offsets[n + 1]);
    int cnt = row_e - row_s;
    int voff = lane * 2;                 // per-lane dword offset into a row

    h16x2 hd2[4], a06[4], a04[4], acc2[4];
    float pd;
    {
        uint2 hv = *reinterpret_cast<const uint2*>(&h[(unsigned)n * 128u + voff]);
        fp8x4_to_h16(hv.x, hd2[0], hd2[1]);
        fp8x4_to_h16(hv.y, hd2[2], hd2[3]);
        float4 av0 = *reinterpret_cast<const float4*>(&a[lane * 8]);
        float4 av1 = *reinterpret_cast<const float4*>(&a[lane * 8 + 4]);
        float aa[8] = {av0.x, av0.y, av0.z, av0.w, av1.x, av1.y, av1.z, av1.w};
        const float L2E = 1.4426950408889634f;
        #pragma unroll
        for (int k = 0; k < 4; k++) {
            a06[k][0] = (_Float16)(aa[2*k]   * (0.6f * L2E));
            a06[k][1] = (_Float16)(aa[2*k+1] * (0.6f * L2E));
            a04[k][0] = (_Float16)(aa[2*k]   * (0.4f * L2E));
            a04[k][1] = (_Float16)(aa[2*k+1] * (0.4f * L2E));
            acc2[k][0] = (_Float16)0.f; acc2[k][1] = (_Float16)0.f;
        }
        float s = 0.f;
        #pragma unroll
        for (int k = 0; k < 4; k++) s = __builtin_amdgcn_fdot2(hd2[k], a06[k], s, false);
        pd = row16_sum(s);
    }

    auto ld = [&](int ii) {   // ii uniform -> s_load of csr_src, saddr h load
        int s = __builtin_amdgcn_readfirstlane(csr_src[row_s + ii]);
        return *reinterpret_cast<const uint2*>(&h[(unsigned)s * 128u + voff]);
    };

    float den = 0.f;
    uint2 rA = make_uint2(0, 0), rB = make_uint2(0, 0);
    if (cnt > 0) rA = ld(0);
    if (cnt > 1) rB = ld(1);

    const float C1 = 0.69314718f, C2 = 0.24022651f, C3 = 0.05550411f;

    auto process = [&](uint2 sv) {
        h16x2 hs[4];
        fp8x4_to_h16(sv.x, hs[0], hs[1]);
        fp8x4_to_h16(sv.y, hs[2], hs[3]);
        float p0 = 0.f, p1 = 0.f;          // two parallel chains (ILP)
        #pragma unroll
        for (int k = 0; k < 2; k++) {
            h16x2 t2 = hs[k] + hd2[k];
            h16x2 at2 = u2h2(h22u(t2) & 0x7FFF7FFFu);
            p0 = __builtin_amdgcn_fdot2(hs[k], a06[k], p0, false);
            p0 = __builtin_amdgcn_fdot2(at2, a04[k], p0, false);
        }
        #pragma unroll
        for (int k = 2; k < 4; k++) {
            h16x2 t2 = hs[k] + hd2[k];
            h16x2 at2 = u2h2(h22u(t2) & 0x7FFF7FFFu);
            p1 = __builtin_amdgcn_fdot2(hs[k], a06[k], p1, false);
            p1 = __builtin_amdgcn_fdot2(at2, a04[k], p1, false);
        }
        float p = row16_sum(p0 + p1) + pd;
        float w = fmaf(p, fmaf(p, fmaf(p, C3, C2), C1), 1.f);
        den += w;
        h16x2 w2 = packf2(w, w);
        #pragma unroll
        for (int k = 0; k < 4; k++) acc2[k] = w2 * hs[k] + acc2[k];
    };

    for (int i = 0; i < cnt; i += 2) {
        {
            uint2 cur = rA;
            rA = ld(min(i + 2, cnt - 1));
            process(cur);
        }
        if (i + 1 < cnt) {
            uint2 cur = rB;
            rB = ld(min(i + 3, cnt - 1));
            process(cur);
        }
    }

    float inv = (den > 0.f) ? 0.25f / den : 0.f;
    float out8[8];
    #pragma unroll
    for (int j = 0; j < 8; j++) {
        float r = (float)acc2[j >> 1][j & 1] * inv;
        r += __shfl_xor(r, 16);
        r += __shfl_xor(r, 32);
        out8[j] = r;
    }
    if constexpr (WRITE_DOTS) {
        int d0 = (lane & 15) * 8;
        float4 wv0 = *reinterpret_cast<const float4*>(&wreg[d0]);
        float4 wv1 = *reinterpret_cast<const float4*>(&wreg[d0 + 4]);
        float pdot = out8[0] * wv0.x + out8[1] * wv0.y + out8[2] * wv0.z + out8[3] * wv0.w
                   + out8[4] * wv1.x + out8[5] * wv1.y + out8[6] * wv1.z + out8[7] * wv1.w;
        pdot = row16_sum(pdot);
        if (lane == 0) dots[n] = pdot;
    } else {
        if (lane < 16) {
            union { unsigned short u[8]; uint4 v; } o;
            #pragma unroll
            for (int j = 0; j < 8; j++) o.u[j] = f2b(out8[j]);
            *reinterpret_cast<uint4*>(&x[(unsigned)n * 128u + lane * 8]) = o.v;
        }
    }
}

// ---------------- h2 = x @ W2 + b2 via MFMA (swapped operands) ----------------
__global__ void __launch_bounds__(256) gemm_kernel(const unsigned short* __restrict__ x,
                                                   const unsigned short* __restrict__ Wb,
                                                   const float* __restrict__ bias,
                                                   unsigned char* __restrict__ hout) {
    int w = threadIdx.x >> 6, l = threadIdx.x & 63;
    int rb = blockIdx.x * 64 + w * 16;
    int cb = blockIdx.y * 64;
    int lr = l & 15, lq = l >> 4;
    f32x4 acc[4] = {};
    int arow = rb + lr;
    bool rok = arow < N_NODES;
    #pragma unroll
    for (int s = 0; s < 4; s++) {
        s16x8 afr = {};
        if (rok) afr = *reinterpret_cast<const s16x8*>(&x[(size_t)arow * 128 + s * 32 + lq * 8]);
        #pragma unroll
        for (int sub = 0; sub < 4; sub++) {
            s16x8 bfr = *reinterpret_cast<const s16x8*>(
                &Wb[(((size_t)(s * 4 + lq) * 512) + cb + sub * 16 + lr) << 3]);
            acc[sub] = __builtin_amdgcn_mfma_f32_16x16x32_bf16(bfr, afr, acc[sub], 0, 0, 0);
        }
    }
    if (!rok) return;
    #pragma unroll
    for (int sub = 0; sub < 4; sub++) {
        int col0 = cb + sub * 16 + lq * 4;
        float4 bb = *reinterpret_cast<const float4*>(&bias[col0]);
        unsigned int pk = __builtin_amdgcn_cvt_pk_fp8_f32(acc[sub][0] + bb.x,
                                                          acc[sub][1] + bb.y, 0, false);
        pk = __builtin_amdgcn_cvt_pk_fp8_f32(acc[sub][2] + bb.z,
                                             acc[sub][3] + bb.w, pk, true);
        *reinterpret_cast<unsigned int*>(&hout[(size_t)arow * 512 + col0]) = pk;
    }
}

// ---------------- pool over per-node dots + fused final (last block) --------
__global__ void __launch_bounds__(256) pool64_kernel(const float* __restrict__ dots,
                                                     const int* __restrict__ gid,
                                                     float* __restrict__ pool,
                                                     int* __restrict__ done,
                                                     float* __restrict__ out) {
    int wave = (blockIdx.x * blockDim.x + threadIdx.x) >> 6;
    int lane = threadIdx.x & 63;
    int n0 = wave * 64;
    if (n0 < N_NODES) {
        int n = n0 + lane;
        int nc = min(n, N_NODES - 1);
        int g = gid[nc];
        float v = (n < N_NODES) ? dots[n] : 0.f;
        int g0 = __shfl(g, 0);
        bool uni = __all(g == g0);
        if (uni) {
            v += __shfl_xor(v, 1);
            v += __shfl_xor(v, 2);
            v += __shfl_xor(v, 4);
            v += __shfl_xor(v, 8);
            v += __shfl_xor(v, 16);
            v += __shfl_xor(v, 32);
            if (lane == 0) atomicAdd(&pool[g0], v);
        } else {
            if (n < N_NODES) atomicAdd(&pool[g], v);   // rare boundary wave
        }
    }
    __threadfence();
    __syncthreads();
    __shared__ int amlast;
    if (threadIdx.x == 0)
        amlast = (atomicAdd(done, 1) == (int)gridDim.x - 1) ? 1 : 0;
    __syncthreads();
    if (amlast && threadIdx.x < G_GRAPHS) {
        // atomic read-back guarantees L2-coherent view of all blocks' sums
        out[threadIdx.x] = atomicAdd(&pool[threadIdx.x], 0.f);
    }
}

extern "C" void kernel_launch(void* const* d_in, const int* in_sizes, int n_in,
                              void* d_out, int out_size, void* d_ws, size_t ws_size,
                              hipStream_t stream) {
    const int* feats = (const int*)d_in[0];
    const int* src   = (const int*)d_in[1];
    const int* dst   = (const int*)d_in[2];
    const int* gids  = (const int*)d_in[3];
    const float* emb  = (const float*)d_in[4];
    const float* W1   = (const float*)d_in[5];
    const float* b1   = (const float*)d_in[6];
    const float* a1   = (const float*)d_in[7];
    const float* W2   = (const float*)d_in[8];
    const float* b2   = (const float*)d_in[9];
    const float* a2   = (const float*)d_in[10];
    const float* wreg = (const float*)d_in[11];
    float* out = (float*)d_out;

    char* ws = (char*)d_ws;
    size_t off = 0;
    auto alloc = [&](size_t bytes) -> void* {
        void* p = ws + off;
        off = (off + bytes + 255) & ~(size_t)255;
        return p;
    };
    int*   counts  = (int*)alloc((size_t)N_NODES * 4);
    int*   offsets = (int*)alloc((size_t)(N_NODES + 1) * 4);
    int*   cursor  = (int*)alloc((size_t)N_NODES * 4);
    int*   csr_src = (int*)alloc((size_t)N_EDGES * 4);
    int*   bsum    = (int*)alloc(64 * 4);
    int*   done    = (int*)alloc(4);
    float* M1      = (float*)alloc((size_t)V_VOCAB * HD * 4);
    unsigned int*   h  = (unsigned int*)alloc((size_t)N_NODES * HD);      // fp8
    unsigned short* x  = (unsigned short*)alloc((size_t)N_NODES * D_DIM * 2);
    unsigned short* Wb = (unsigned short*)alloc((size_t)D_DIM * HD * 2);
    float* dots    = (float*)alloc((size_t)N_NODES * 4);
    float* pool    = (float*)alloc((size_t)G_GRAPHS * 4);

    prep_kernel<<<PREP_M1_BLOCKS + PREP_WSZ_BLOCKS + PREP_CNT_BLOCKS, 256, 0, stream>>>(
        emb, W1, M1, W2, Wb, counts, done);
    hist_kernel<<<(N_EDGES + 255) / 256, 256, 0, stream>>>(dst, counts, pool);
    scan1_kernel<<<64, 256, 0, stream>>>(counts, offsets, bsum);
    scan23_kernel<<<64, 256, 0, stream>>>(counts, offsets, bsum, cursor);
    scatter_kernel<<<(N_EDGES + 255) / 256, 256, 0, stream>>>(src, dst, cursor, csr_src);

    gather_kernel<<<(N_NODES * HD / 8) / 256, 256, 0, stream>>>(feats, M1, b1, h);

    gat_kernel<false><<<(N_NODES + 3) / 4, 256, 0, stream>>>(h, offsets, csr_src, a1,
                                                             wreg, x, dots);
    gemm_kernel<<<dim3((N_NODES + 63) / 64, 8), 256, 0, stream>>>(x, Wb, b2, (unsigned char*)h);
    gat_kernel<true><<<(N_NODES + 3) / 4, 256, 0, stream>>>(h, offsets, csr_src, a2,
                                                            wreg, x, dots);

    pool64_kernel<<<(N_NODES / 64 + 4) / 4, 256, 0, stream>>>(dots, gids, pool, done, out);
}

// Round 16
// 332.374 us; speedup vs baseline: 1.1028x; 1.0085x over previous
//
#include <hip/hip_runtime.h>
#include <hip/hip_bf16.h>

#define N_NODES 50000
#define N_EDGES 800000
#define G_GRAPHS 64
#define H_HEADS 4
#define D_DIM 128
#define HD 512
#define V_VOCAB 128
#define NEG_SLOPE 0.2f

typedef float f32x2v __attribute__((ext_vector_type(2)));
typedef float f32x4 __attribute__((ext_vector_type(4)));
typedef short s16x8 __attribute__((ext_vector_type(8)));
typedef _Float16 h16x2 __attribute__((ext_vector_type(2)));

static __device__ __forceinline__ unsigned short f2b(float f) {
    union { float f; unsigned int i; } x; x.f = f;
    unsigned int r = x.i + 0x7fffu + ((x.i >> 16) & 1u);
    return (unsigned short)(r >> 16);
}
static __device__ __forceinline__ h16x2 u2h2(unsigned int u) {
    union { unsigned int u; h16x2 h; } c; c.u = u; return c.h;
}
static __device__ __forceinline__ unsigned int h22u(h16x2 h) {
    union { unsigned int u; h16x2 h; } c; c.h = h; return c.u;
}
static __device__ __forceinline__ h16x2 packf2(float lo, float hi) {
    union { __fp16 __attribute__((ext_vector_type(2))) p; h16x2 h; } c;
    c.p = __builtin_amdgcn_cvt_pkrtz(lo, hi);
    return c.h;
}

// unpack 4 fp8 (one dword) -> 2 h16x2
#if __has_builtin(__builtin_amdgcn_cvt_scalef32_pk_f16_fp8)
static __device__ __forceinline__ void fp8x4_to_h16(unsigned int u, h16x2& h0, h16x2& h1) {
    auto r0 = __builtin_amdgcn_cvt_scalef32_pk_f16_fp8((int)u, 1.0f, false);
    auto r1 = __builtin_amdgcn_cvt_scalef32_pk_f16_fp8((int)u, 1.0f, true);
    union { decltype(r0) p; h16x2 h; } c0, c1;
    c0.p = r0; c1.p = r1;
    h0 = c0.h; h1 = c1.h;
}
#else
static __device__ __forceinline__ void fp8x4_to_h16(unsigned int u, h16x2& h0, h16x2& h1) {
    f32x2v lo = __builtin_amdgcn_cvt_pk_f32_fp8(u, false);
    f32x2v hi = __builtin_amdgcn_cvt_pk_f32_fp8(u, true);
    h0 = packf2(lo.x, lo.y);
    h1 = packf2(hi.x, hi.y);
}
#endif

// butterfly-add over the 16-lane row via DPP (VALU pipe, no LDS latency)
template<int CTRL>
static __device__ __forceinline__ float dpp_add(float v) {
    union { float f; int i; } a, b;
    a.f = v;
    b.i = __builtin_amdgcn_mov_dpp(a.i, CTRL, 0xF, 0xF, true);
    return v + b.f;
}
static __device__ __forceinline__ float row16_sum(float p) {
    p = dpp_add<0xB1>(p);    // quad_perm [1,0,3,2]  : xor 1
    p = dpp_add<0x4E>(p);    // quad_perm [2,3,0,1]  : xor 2
    p = dpp_add<0x141>(p);   // ROW_HALF_MIRROR      : cross-quad in 8
    p = dpp_add<0x140>(p);   // ROW_MIRROR           : cross-8 in 16
    return p;
}

// ---------------- mega: M1=emb@W1 | W2 swizzle | hist | pool zero ----------
#define MEGA_M1_BLOCKS   256
#define MEGA_WSZ_BLOCKS  256
#define MEGA_HIST_BLOCKS ((N_EDGES + 255) / 256)   // 3125
__global__ void __launch_bounds__(256) mega_kernel(const float* __restrict__ emb,
                                                   const float* __restrict__ W1,
                                                   float* __restrict__ M1,
                                                   const float* __restrict__ W2,
                                                   unsigned short* __restrict__ Wb,
                                                   const int* __restrict__ dst,
                                                   int* __restrict__ counts,
                                                   float* __restrict__ pool) {
    int b = blockIdx.x;
    if (b < MEGA_M1_BLOCKS) {
        int idx = b * 256 + threadIdx.x;   // 65536
        int v = idx >> 9, c = idx & 511;
        float acc = 0.f;
        for (int k = 0; k < 128; k++)
            acc += emb[v * 128 + k] * W1[k * 512 + c];
        M1[idx] = acc;
    } else if (b < MEGA_M1_BLOCKS + MEGA_WSZ_BLOCKS) {
        int idx = (b - MEGA_M1_BLOCKS) * 256 + threadIdx.x;   // 65536
        int j = idx & 7, c = (idx >> 3) & 511, qq = idx >> 12;
        Wb[idx] = f2b(W2[(qq * 8 + j) * 512 + c]);
    } else {
        int hb = b - MEGA_M1_BLOCKS - MEGA_WSZ_BLOCKS;
        if (hb == 0 && threadIdx.x < G_GRAPHS) pool[threadIdx.x] = 0.f;
        int i = hb * 256 + threadIdx.x;
        if (i < N_EDGES) atomicAdd(&counts[dst[i]], 1);
    }
}

// ---------------- fused CSR scan (scan1+scan23, device-scope flag sync) -----
// 64 blocks << 256 CUs -> co-residency guaranteed; bsum read via atomics for
// cross-XCD coherence.
__global__ void __launch_bounds__(256) scanf_kernel(const int* __restrict__ counts,
                                                    int* __restrict__ offsets,
                                                    int* __restrict__ cursor,
                                                    int* __restrict__ bsum,
                                                    int* __restrict__ flag) {
    __shared__ int buf[256];
    __shared__ int sbase;
    int t = threadIdx.x, b = blockIdx.x;
    int i0 = (b * 256 + t) * 4;
    int v[4], c[4], s = 0;
    #pragma unroll
    for (int j = 0; j < 4; j++) {
        int idx = i0 + j;
        v[j] = (idx < N_NODES) ? counts[idx] : 0;
        s += v[j];
        c[j] = s;
    }
    buf[t] = s;
    __syncthreads();
    for (int off = 1; off < 256; off <<= 1) {
        int add = (t >= off) ? buf[t - off] : 0;
        __syncthreads();
        buf[t] += add;
        __syncthreads();
    }
    int ebase = (t > 0) ? buf[t - 1] : 0;
    if (t == 0) {
        bsum[b] = buf[255];
        __threadfence();
        atomicAdd(flag, 1);
        while (atomicAdd(flag, 0) < 64) __builtin_amdgcn_s_sleep(8);
    }
    __syncthreads();
    if (t < 64) {
        int vv = (t < b) ? atomicAdd(&bsum[t], 0) : 0;
        #pragma unroll
        for (int off = 1; off < 64; off <<= 1) vv += __shfl_xor(vv, off);
        if (t == 0) sbase = vv;
    }
    __syncthreads();
    int base = sbase;
    #pragma unroll
    for (int j = 0; j < 4; j++) {
        int idx = i0 + j;
        if (idx < N_NODES) {
            int e = base + ebase + c[j];
            offsets[idx + 1] = e;
            cursor[idx] = e - v[j];
        }
    }
    if (b == 0 && t == 0) offsets[0] = 0;
}

// ---------------- scatter | gather (independent, grid-partitioned) ----------
#define SG_SCAT_BLOCKS ((N_EDGES + 255) / 256)     // 3125
#define SG_GATH_BLOCKS (N_NODES * HD / 8 / 256)    // 12500
__global__ void __launch_bounds__(256) scatgath_kernel(const int* __restrict__ src,
                                                       const int* __restrict__ dst,
                                                       int* __restrict__ cursor,
                                                       int* __restrict__ csr_src,
                                                       const int* __restrict__ feats,
                                                       const float* __restrict__ M1,
                                                       const float* __restrict__ b1,
                                                       unsigned int* __restrict__ h) {
    int b = blockIdx.x;
    if (b < SG_SCAT_BLOCKS) {
        int i = b * 256 + threadIdx.x;
        if (i < N_EDGES) {
            int d = dst[i];
            int pos = atomicAdd(&cursor[d], 1);
            csr_src[pos] = src[i];
        }
    } else {
        int tid = (b - SG_SCAT_BLOCKS) * 256 + threadIdx.x;
        int i0 = tid * 8;
        int n = i0 >> 9, c = i0 & 511;
        if (n >= N_NODES) return;
        int f = feats[n];
        const float* mrow = &M1[f * 512 + c];
        float v[8];
        #pragma unroll
        for (int j = 0; j < 8; j++) v[j] = mrow[j] + b1[c + j];
        uint2 o;
        o.x = __builtin_amdgcn_cvt_pk_fp8_f32(v[0], v[1], 0, false);
        o.x = __builtin_amdgcn_cvt_pk_fp8_f32(v[2], v[3], o.x, true);
        o.y = __builtin_amdgcn_cvt_pk_fp8_f32(v[4], v[5], 0, false);
        o.y = __builtin_amdgcn_cvt_pk_fp8_f32(v[6], v[7], o.y, true);
        *reinterpret_cast<uint2*>(&h[i0 >> 2]) = o;
    }
}

// ---------------- GATv2 layer (frozen from round 15) ----------------
template<bool WRITE_DOTS>
__global__ void __launch_bounds__(256) gat_kernel(const unsigned int* __restrict__ h,
                                                  const int* __restrict__ offsets,
                                                  const int* __restrict__ csr_src,
                                                  const float* __restrict__ a,
                                                  const float* __restrict__ wreg,
                                                  unsigned short* __restrict__ x,
                                                  float* __restrict__ dots) {
    int wid = threadIdx.x >> 6;
    int lane = threadIdx.x & 63;
    int n = blockIdx.x * 4 + wid;
    if (n >= N_NODES) return;
    n = __builtin_amdgcn_readfirstlane(n);
    int row_s = __builtin_amdgcn_readfirstlane(offsets[n]);
    int row_e = __builtin_amdgcn_readfirstlane(offsets[n + 1]);
    int cnt = row_e - row_s;
    int voff = lane * 2;                 // per-lane dword offset into a row

    h16x2 hd2[4], a06[4], a04[4], acc2[4];
    float pd;
    {
        uint2 hv = *reinterpret_cast<const uint2*>(&h[(unsigned)n * 128u + voff]);
        fp8x4_to_h16(hv.x, hd2[0], hd2[1]);
        fp8x4_to_h16(hv.y, hd2[2], hd2[3]);
        float4 av0 = *reinterpret_cast<const float4*>(&a[lane * 8]);
        float4 av1 = *reinterpret_cast<const float4*>(&a[lane * 8 + 4]);
        float aa[8] = {av0.x, av0.y, av0.z, av0.w, av1.x, av1.y, av1.z, av1.w};
        const float L2E = 1.4426950408889634f;
        #pragma unroll
        for (int k = 0; k < 4; k++) {
            a06[k][0] = (_Float16)(aa[2*k]   * (0.6f * L2E));
            a06[k][1] = (_Float16)(aa[2*k+1] * (0.6f * L2E));
            a04[k][0] = (_Float16)(aa[2*k]   * (0.4f * L2E));
            a04[k][1] = (_Float16)(aa[2*k+1] * (0.4f * L2E));
            acc2[k][0] = (_Float16)0.f; acc2[k][1] = (_Float16)0.f;
        }
        float s = 0.f;
        #pragma unroll
        for (int k = 0; k < 4; k++) s = __builtin_amdgcn_fdot2(hd2[k], a06[k], s, false);
        pd = row16_sum(s);
    }

    auto ld = [&](int ii) {   // ii uniform -> s_load of csr_src, saddr h load
        int s = __builtin_amdgcn_readfirstlane(csr_src[row_s + ii]);
        return *reinterpret_cast<const uint2*>(&h[(unsigned)s * 128u + voff]);
    };

    float den = 0.f;
    uint2 rA = make_uint2(0, 0), rB = make_uint2(0, 0);
    if (cnt > 0) rA = ld(0);
    if (cnt > 1) rB = ld(1);

    const float C1 = 0.69314718f, C2 = 0.24022651f, C3 = 0.05550411f;

    auto process = [&](uint2 sv) {
        h16x2 hs[4];
        fp8x4_to_h16(sv.x, hs[0], hs[1]);
        fp8x4_to_h16(sv.y, hs[2], hs[3]);
        float p0 = 0.f, p1 = 0.f;          // two parallel chains (ILP)
        #pragma unroll
        for (int k = 0; k < 2; k++) {
            h16x2 t2 = hs[k] + hd2[k];
            h16x2 at2 = u2h2(h22u(t2) & 0x7FFF7FFFu);
            p0 = __builtin_amdgcn_fdot2(hs[k], a06[k], p0, false);
            p0 = __builtin_amdgcn_fdot2(at2, a04[k], p0, false);
        }
        #pragma unroll
        for (int k = 2; k < 4; k++) {
            h16x2 t2 = hs[k] + hd2[k];
            h16x2 at2 = u2h2(h22u(t2) & 0x7FFF7FFFu);
            p1 = __builtin_amdgcn_fdot2(hs[k], a06[k], p1, false);
            p1 = __builtin_amdgcn_fdot2(at2, a04[k], p1, false);
        }
        float p = row16_sum(p0 + p1) + pd;
        float w = fmaf(p, fmaf(p, fmaf(p, C3, C2), C1), 1.f);
        den += w;
        h16x2 w2 = packf2(w, w);
        #pragma unroll
        for (int k = 0; k < 4; k++) acc2[k] = w2 * hs[k] + acc2[k];
    };

    for (int i = 0; i < cnt; i += 2) {
        {
            uint2 cur = rA;
            rA = ld(min(i + 2, cnt - 1));
            process(cur);
        }
        if (i + 1 < cnt) {
            uint2 cur = rB;
            rB = ld(min(i + 3, cnt - 1));
            process(cur);
        }
    }

    float inv = (den > 0.f) ? 0.25f / den : 0.f;
    float out8[8];
    #pragma unroll
    for (int j = 0; j < 8; j++) {
        float r = (float)acc2[j >> 1][j & 1] * inv;
        r += __shfl_xor(r, 16);
        r += __shfl_xor(r, 32);
        out8[j] = r;
    }
    if constexpr (WRITE_DOTS) {
        int d0 = (lane & 15) * 8;
        float4 wv0 = *reinterpret_cast<const float4*>(&wreg[d0]);
        float4 wv1 = *reinterpret_cast<const float4*>(&wreg[d0 + 4]);
        float pdot = out8[0] * wv0.x + out8[1] * wv0.y + out8[2] * wv0.z + out8[3] * wv0.w
                   + out8[4] * wv1.x + out8[5] * wv1.y + out8[6] * wv1.z + out8[7] * wv1.w;
        pdot = row16_sum(pdot);
        if (lane == 0) dots[n] = pdot;
    } else {
        if (lane < 16) {
            union { unsigned short u[8]; uint4 v; } o;
            #pragma unroll
            for (int j = 0; j < 8; j++) o.u[j] = f2b(out8[j]);
            *reinterpret_cast<uint4*>(&x[(unsigned)n * 128u + lane * 8]) = o.v;
        }
    }
}

// ---------------- h2 = x @ W2 + b2 via MFMA (swapped operands) ----------------
__global__ void __launch_bounds__(256) gemm_kernel(const unsigned short* __restrict__ x,
                                                   const unsigned short* __restrict__ Wb,
                                                   const float* __restrict__ bias,
                                                   unsigned char* __restrict__ hout) {
    int w = threadIdx.x >> 6, l = threadIdx.x & 63;
    int rb = blockIdx.x * 64 + w * 16;
    int cb = blockIdx.y * 64;
    int lr = l & 15, lq = l >> 4;
    f32x4 acc[4] = {};
    int arow = rb + lr;
    bool rok = arow < N_NODES;
    #pragma unroll
    for (int s = 0; s < 4; s++) {
        s16x8 afr = {};
        if (rok) afr = *reinterpret_cast<const s16x8*>(&x[(size_t)arow * 128 + s * 32 + lq * 8]);
        #pragma unroll
        for (int sub = 0; sub < 4; sub++) {
            s16x8 bfr = *reinterpret_cast<const s16x8*>(
                &Wb[(((size_t)(s * 4 + lq) * 512) + cb + sub * 16 + lr) << 3]);
            acc[sub] = __builtin_amdgcn_mfma_f32_16x16x32_bf16(bfr, afr, acc[sub], 0, 0, 0);
        }
    }
    if (!rok) return;
    #pragma unroll
    for (int sub = 0; sub < 4; sub++) {
        int col0 = cb + sub * 16 + lq * 4;
        float4 bb = *reinterpret_cast<const float4*>(&bias[col0]);
        unsigned int pk = __builtin_amdgcn_cvt_pk_fp8_f32(acc[sub][0] + bb.x,
                                                          acc[sub][1] + bb.y, 0, false);
        pk = __builtin_amdgcn_cvt_pk_fp8_f32(acc[sub][2] + bb.z,
                                             acc[sub][3] + bb.w, pk, true);
        *reinterpret_cast<unsigned int*>(&hout[(size_t)arow * 512 + col0]) = pk;
    }
}

// ---------------- pool over per-node dots + fused final (last block) --------
__global__ void __launch_bounds__(256) pool64_kernel(const float* __restrict__ dots,
                                                     const int* __restrict__ gid,
                                                     float* __restrict__ pool,
                                                     int* __restrict__ done,
                                                     float* __restrict__ out) {
    int wave = (blockIdx.x * blockDim.x + threadIdx.x) >> 6;
    int lane = threadIdx.x & 63;
    int n0 = wave * 64;
    if (n0 < N_NODES) {
        int n = n0 + lane;
        int nc = min(n, N_NODES - 1);
        int g = gid[nc];
        float v = (n < N_NODES) ? dots[n] : 0.f;
        int g0 = __shfl(g, 0);
        bool uni = __all(g == g0);
        if (uni) {
            v += __shfl_xor(v, 1);
            v += __shfl_xor(v, 2);
            v += __shfl_xor(v, 4);
            v += __shfl_xor(v, 8);
            v += __shfl_xor(v, 16);
            v += __shfl_xor(v, 32);
            if (lane == 0) atomicAdd(&pool[g0], v);
        } else {
            if (n < N_NODES) atomicAdd(&pool[g], v);   // rare boundary wave
        }
    }
    __threadfence();
    __syncthreads();
    __shared__ int amlast;
    if (threadIdx.x == 0)
        amlast = (atomicAdd(done, 1) == (int)gridDim.x - 1) ? 1 : 0;
    __syncthreads();
    if (amlast && threadIdx.x < G_GRAPHS) {
        out[threadIdx.x] = atomicAdd(&pool[threadIdx.x], 0.f);
    }
}

extern "C" void kernel_launch(void* const* d_in, const int* in_sizes, int n_in,
                              void* d_out, int out_size, void* d_ws, size_t ws_size,
                              hipStream_t stream) {
    const int* feats = (const int*)d_in[0];
    const int* src   = (const int*)d_in[1];
    const int* dst   = (const int*)d_in[2];
    const int* gids  = (const int*)d_in[3];
    const float* emb  = (const float*)d_in[4];
    const float* W1   = (const float*)d_in[5];
    const float* b1   = (const float*)d_in[6];
    const float* a1   = (const float*)d_in[7];
    const float* W2   = (const float*)d_in[8];
    const float* b2   = (const float*)d_in[9];
    const float* a2   = (const float*)d_in[10];
    const float* wreg = (const float*)d_in[11];
    float* out = (float*)d_out;

    char* ws = (char*)d_ws;
    size_t off = 0;
    auto alloc = [&](size_t bytes) -> void* {
        void* p = ws + off;
        off = (off + bytes + 255) & ~(size_t)255;
        return p;
    };
    // counts + flag + done live in one memset-covered region
    int*   counts  = (int*)alloc((size_t)N_NODES * 4 + 8);
    int*   flag    = counts + N_NODES;       // scanF sync counter
    int*   done    = counts + N_NODES + 1;   // pool64 completion counter
    int*   offsets = (int*)alloc((size_t)(N_NODES + 1) * 4);
    int*   cursor  = (int*)alloc((size_t)N_NODES * 4);
    int*   csr_src = (int*)alloc((size_t)N_EDGES * 4);
    int*   bsum    = (int*)alloc(64 * 4);
    float* M1      = (float*)alloc((size_t)V_VOCAB * HD * 4);
    unsigned int*   h  = (unsigned int*)alloc((size_t)N_NODES * HD);      // fp8
    unsigned short* x  = (unsigned short*)alloc((size_t)N_NODES * D_DIM * 2);
    unsigned short* Wb = (unsigned short*)alloc((size_t)D_DIM * HD * 2);
    float* dots    = (float*)alloc((size_t)N_NODES * 4);
    float* pool    = (float*)alloc((size_t)G_GRAPHS * 4);

    hipMemsetAsync(counts, 0, (size_t)N_NODES * 4 + 8, stream);

    mega_kernel<<<MEGA_M1_BLOCKS + MEGA_WSZ_BLOCKS + MEGA_HIST_BLOCKS, 256, 0, stream>>>(
        emb, W1, M1, W2, Wb, dst, counts, pool);
    scanf_kernel<<<64, 256, 0, stream>>>(counts, offsets, cursor, bsum, flag);
    scatgath_kernel<<<SG_SCAT_BLOCKS + SG_GATH_BLOCKS, 256, 0, stream>>>(
        src, dst, cursor, csr_src, feats, M1, b1, h);

    gat_kernel<false><<<(N_NODES + 3) / 4, 256, 0, stream>>>(h, offsets, csr_src, a1,
                                                             wreg, x, dots);
    gemm_kernel<<<dim3((N_NODES + 63) / 64, 8), 256, 0, stream>>>(x, Wb, b2, (unsigned char*)h);
    gat_kernel<true><<<(N_NODES + 3) / 4, 256, 0, stream>>>(h, offsets, csr_src, a2,
                                                            wreg, x, dots);

    pool64_kernel<<<(N_NODES / 64 + 4) / 4, 256, 0, stream>>>(dots, gids, pool, done, out);
}

// Round 17
// 329.028 us; speedup vs baseline: 1.1140x; 1.0102x over previous
//
#include <hip/hip_runtime.h>
#include <hip/hip_bf16.h>

#define N_NODES 50000
#define N_EDGES 800000
#define G_GRAPHS 64
#define H_HEADS 4
#define D_DIM 128
#define HD 512
#define V_VOCAB 128
#define NEG_SLOPE 0.2f

typedef float f32x2v __attribute__((ext_vector_type(2)));
typedef float f32x4 __attribute__((ext_vector_type(4)));
typedef short s16x8 __attribute__((ext_vector_type(8)));
typedef _Float16 h16x2 __attribute__((ext_vector_type(2)));

static __device__ __forceinline__ unsigned short f2b(float f) {
    union { float f; unsigned int i; } x; x.f = f;
    unsigned int r = x.i + 0x7fffu + ((x.i >> 16) & 1u);
    return (unsigned short)(r >> 16);
}
static __device__ __forceinline__ h16x2 u2h2(unsigned int u) {
    union { unsigned int u; h16x2 h; } c; c.u = u; return c.h;
}
static __device__ __forceinline__ unsigned int h22u(h16x2 h) {
    union { unsigned int u; h16x2 h; } c; c.h = h; return c.u;
}
static __device__ __forceinline__ h16x2 packf2(float lo, float hi) {
    union { __fp16 __attribute__((ext_vector_type(2))) p; h16x2 h; } c;
    c.p = __builtin_amdgcn_cvt_pkrtz(lo, hi);
    return c.h;
}

// unpack 4 fp8 (one dword) -> 2 h16x2
#if __has_builtin(__builtin_amdgcn_cvt_scalef32_pk_f16_fp8)
static __device__ __forceinline__ void fp8x4_to_h16(unsigned int u, h16x2& h0, h16x2& h1) {
    auto r0 = __builtin_amdgcn_cvt_scalef32_pk_f16_fp8((int)u, 1.0f, false);
    auto r1 = __builtin_amdgcn_cvt_scalef32_pk_f16_fp8((int)u, 1.0f, true);
    union { decltype(r0) p; h16x2 h; } c0, c1;
    c0.p = r0; c1.p = r1;
    h0 = c0.h; h1 = c1.h;
}
#else
static __device__ __forceinline__ void fp8x4_to_h16(unsigned int u, h16x2& h0, h16x2& h1) {
    f32x2v lo = __builtin_amdgcn_cvt_pk_f32_fp8(u, false);
    f32x2v hi = __builtin_amdgcn_cvt_pk_f32_fp8(u, true);
    h0 = packf2(lo.x, lo.y);
    h1 = packf2(hi.x, hi.y);
}
#endif

// butterfly-add over the 16-lane row via DPP (VALU pipe, no LDS latency)
template<int CTRL>
static __device__ __forceinline__ float dpp_add(float v) {
    union { float f; int i; } a, b;
    a.f = v;
    b.i = __builtin_amdgcn_mov_dpp(a.i, CTRL, 0xF, 0xF, true);
    return v + b.f;
}
static __device__ __forceinline__ float row16_sum(float p) {
    p = dpp_add<0xB1>(p);    // quad_perm [1,0,3,2]  : xor 1
    p = dpp_add<0x4E>(p);    // quad_perm [2,3,0,1]  : xor 2
    p = dpp_add<0x141>(p);   // ROW_HALF_MIRROR      : cross-quad in 8
    p = dpp_add<0x140>(p);   // ROW_MIRROR           : cross-8 in 16
    return p;
}

// ---- mega: M1b = fp8(emb@W1 + b1) (128x512, 64KB) | Wb swizzle | hist | pool0
// Layer-1 h has only 128 distinct rows (h[n] = M1b[feats[n]]) -> no h buffer.
#define MEGA_M1_BLOCKS   64
#define MEGA_WSZ_BLOCKS  256
#define MEGA_HIST_BLOCKS ((N_EDGES + 255) / 256)   // 3125
__global__ void __launch_bounds__(256) mega_kernel(const float* __restrict__ emb,
                                                   const float* __restrict__ W1,
                                                   const float* __restrict__ b1,
                                                   unsigned int* __restrict__ M1b,
                                                   const float* __restrict__ W2,
                                                   unsigned short* __restrict__ Wb,
                                                   const int* __restrict__ dst,
                                                   int* __restrict__ counts,
                                                   float* __restrict__ pool) {
    int b = blockIdx.x;
    if (b < MEGA_M1_BLOCKS) {
        int idx = b * 256 + threadIdx.x;     // 16384 threads, 4 cols each
        int v = idx >> 7, c0 = (idx & 127) * 4;
        float acc[4] = {b1[c0], b1[c0 + 1], b1[c0 + 2], b1[c0 + 3]};
        for (int k = 0; k < 128; k++) {
            float e = emb[v * 128 + k];
            #pragma unroll
            for (int j = 0; j < 4; j++) acc[j] = fmaf(e, W1[k * 512 + c0 + j], acc[j]);
        }
        unsigned int pk = __builtin_amdgcn_cvt_pk_fp8_f32(acc[0], acc[1], 0, false);
        pk = __builtin_amdgcn_cvt_pk_fp8_f32(acc[2], acc[3], pk, true);
        M1b[idx] = pk;
    } else if (b < MEGA_M1_BLOCKS + MEGA_WSZ_BLOCKS) {
        int idx = (b - MEGA_M1_BLOCKS) * 256 + threadIdx.x;   // 65536
        int j = idx & 7, c = (idx >> 3) & 511, qq = idx >> 12;
        Wb[idx] = f2b(W2[(qq * 8 + j) * 512 + c]);
    } else {
        int hb = b - MEGA_M1_BLOCKS - MEGA_WSZ_BLOCKS;
        if (hb == 0 && threadIdx.x < G_GRAPHS) pool[threadIdx.x] = 0.f;
        int i = hb * 256 + threadIdx.x;
        if (i < N_EDGES) atomicAdd(&counts[dst[i]], 1);
    }
}

// ---------------- fused CSR scan (device-scope flag sync, 64 blocks) --------
__global__ void __launch_bounds__(256) scanf_kernel(const int* __restrict__ counts,
                                                    int* __restrict__ offsets,
                                                    int* __restrict__ cursor,
                                                    int* __restrict__ bsum,
                                                    int* __restrict__ flag) {
    __shared__ int buf[256];
    __shared__ int sbase;
    int t = threadIdx.x, b = blockIdx.x;
    int i0 = (b * 256 + t) * 4;
    int v[4], c[4], s = 0;
    #pragma unroll
    for (int j = 0; j < 4; j++) {
        int idx = i0 + j;
        v[j] = (idx < N_NODES) ? counts[idx] : 0;
        s += v[j];
        c[j] = s;
    }
    buf[t] = s;
    __syncthreads();
    for (int off = 1; off < 256; off <<= 1) {
        int add = (t >= off) ? buf[t - off] : 0;
        __syncthreads();
        buf[t] += add;
        __syncthreads();
    }
    int ebase = (t > 0) ? buf[t - 1] : 0;
    if (t == 0) {
        bsum[b] = buf[255];
        __threadfence();
        atomicAdd(flag, 1);
        while (atomicAdd(flag, 0) < 64) __builtin_amdgcn_s_sleep(8);
    }
    __syncthreads();
    if (t < 64) {
        int vv = (t < b) ? atomicAdd(&bsum[t], 0) : 0;
        #pragma unroll
        for (int off = 1; off < 64; off <<= 1) vv += __shfl_xor(vv, off);
        if (t == 0) sbase = vv;
    }
    __syncthreads();
    int base = sbase;
    #pragma unroll
    for (int j = 0; j < 4; j++) {
        int idx = i0 + j;
        if (idx < N_NODES) {
            int e = base + ebase + c[j];
            offsets[idx + 1] = e;
            cursor[idx] = e - v[j];
        }
    }
    if (b == 0 && t == 0) offsets[0] = 0;
}

// ---------------- scatter ----------------
__global__ void scatter_kernel(const int* __restrict__ src, const int* __restrict__ dst,
                               int* __restrict__ cursor, int* __restrict__ csr_src) {
    int i = blockIdx.x * blockDim.x + threadIdx.x;
    if (i < N_EDGES) {
        int d = dst[i];
        int pos = atomicAdd(&cursor[d], 1);
        csr_src[pos] = src[i];
    }
}

// ---------------- GATv2 layer ----------------
// LAYER1: rows indexed via feats (128-distinct-row table M1b, L2-resident);
//         writes x. Else: rows = h2 direct; writes dot(x_row,wreg) per node.
template<bool LAYER1>
__global__ void __launch_bounds__(256) gat_kernel(const unsigned int* __restrict__ h,
                                                  const int* __restrict__ offsets,
                                                  const int* __restrict__ csr_src,
                                                  const int* __restrict__ feats,
                                                  const float* __restrict__ a,
                                                  const float* __restrict__ wreg,
                                                  unsigned short* __restrict__ x,
                                                  float* __restrict__ dots) {
    int wid = threadIdx.x >> 6;
    int lane = threadIdx.x & 63;
    int n = blockIdx.x * 4 + wid;
    if (n >= N_NODES) return;
    n = __builtin_amdgcn_readfirstlane(n);
    int row_s = __builtin_amdgcn_readfirstlane(offsets[n]);
    int row_e = __builtin_amdgcn_readfirstlane(offsets[n + 1]);
    int cnt = row_e - row_s;
    int voff = lane * 2;                 // per-lane dword offset into a row

    h16x2 hd2[4], a06[4], a04[4], acc2[4];
    float pd;
    {
        int nr = LAYER1 ? __builtin_amdgcn_readfirstlane(feats[n]) : n;
        uint2 hv = *reinterpret_cast<const uint2*>(&h[(unsigned)nr * 128u + voff]);
        fp8x4_to_h16(hv.x, hd2[0], hd2[1]);
        fp8x4_to_h16(hv.y, hd2[2], hd2[3]);
        float4 av0 = *reinterpret_cast<const float4*>(&a[lane * 8]);
        float4 av1 = *reinterpret_cast<const float4*>(&a[lane * 8 + 4]);
        float aa[8] = {av0.x, av0.y, av0.z, av0.w, av1.x, av1.y, av1.z, av1.w};
        const float L2E = 1.4426950408889634f;
        #pragma unroll
        for (int k = 0; k < 4; k++) {
            a06[k][0] = (_Float16)(aa[2*k]   * (0.6f * L2E));
            a06[k][1] = (_Float16)(aa[2*k+1] * (0.6f * L2E));
            a04[k][0] = (_Float16)(aa[2*k]   * (0.4f * L2E));
            a04[k][1] = (_Float16)(aa[2*k+1] * (0.4f * L2E));
            acc2[k][0] = (_Float16)0.f; acc2[k][1] = (_Float16)0.f;
        }
        float s = 0.f;
        #pragma unroll
        for (int k = 0; k < 4; k++) s = __builtin_amdgcn_fdot2(hd2[k], a06[k], s, false);
        pd = row16_sum(s);
    }

    auto ld = [&](int ii) {   // uniform index chain -> scalar loads, saddr row
        int s = __builtin_amdgcn_readfirstlane(csr_src[row_s + ii]);
        if (LAYER1) s = __builtin_amdgcn_readfirstlane(feats[s]);
        return *reinterpret_cast<const uint2*>(&h[(unsigned)s * 128u + voff]);
    };

    float den = 0.f;
    uint2 rA = make_uint2(0, 0), rB = make_uint2(0, 0);
    if (cnt > 0) rA = ld(0);
    if (cnt > 1) rB = ld(1);

    const float C1 = 0.69314718f, C2 = 0.24022651f, C3 = 0.05550411f;

    auto process = [&](uint2 sv) {
        h16x2 hs[4];
        fp8x4_to_h16(sv.x, hs[0], hs[1]);
        fp8x4_to_h16(sv.y, hs[2], hs[3]);
        float p0 = 0.f, p1 = 0.f;          // two parallel chains (ILP)
        #pragma unroll
        for (int k = 0; k < 2; k++) {
            h16x2 t2 = hs[k] + hd2[k];
            h16x2 at2 = u2h2(h22u(t2) & 0x7FFF7FFFu);
            p0 = __builtin_amdgcn_fdot2(hs[k], a06[k], p0, false);
            p0 = __builtin_amdgcn_fdot2(at2, a04[k], p0, false);
        }
        #pragma unroll
        for (int k = 2; k < 4; k++) {
            h16x2 t2 = hs[k] + hd2[k];
            h16x2 at2 = u2h2(h22u(t2) & 0x7FFF7FFFu);
            p1 = __builtin_amdgcn_fdot2(hs[k], a06[k], p1, false);
            p1 = __builtin_amdgcn_fdot2(at2, a04[k], p1, false);
        }
        float p = row16_sum(p0 + p1) + pd;
        float w = fmaf(p, fmaf(p, fmaf(p, C3, C2), C1), 1.f);
        den += w;
        h16x2 w2 = packf2(w, w);
        #pragma unroll
        for (int k = 0; k < 4; k++) acc2[k] = w2 * hs[k] + acc2[k];
    };

    for (int i = 0; i < cnt; i += 2) {
        {
            uint2 cur = rA;
            rA = ld(min(i + 2, cnt - 1));
            process(cur);
        }
        if (i + 1 < cnt) {
            uint2 cur = rB;
            rB = ld(min(i + 3, cnt - 1));
            process(cur);
        }
    }

    float inv = (den > 0.f) ? 0.25f / den : 0.f;
    float out8[8];
    #pragma unroll
    for (int j = 0; j < 8; j++) {
        float r = (float)acc2[j >> 1][j & 1] * inv;
        r += __shfl_xor(r, 16);
        r += __shfl_xor(r, 32);
        out8[j] = r;
    }
    if constexpr (LAYER1) {
        if (lane < 16) {
            union { unsigned short u[8]; uint4 v; } o;
            #pragma unroll
            for (int j = 0; j < 8; j++) o.u[j] = f2b(out8[j]);
            *reinterpret_cast<uint4*>(&x[(unsigned)n * 128u + lane * 8]) = o.v;
        }
    } else {
        int d0 = (lane & 15) * 8;
        float4 wv0 = *reinterpret_cast<const float4*>(&wreg[d0]);
        float4 wv1 = *reinterpret_cast<const float4*>(&wreg[d0 + 4]);
        float pdot = out8[0] * wv0.x + out8[1] * wv0.y + out8[2] * wv0.z + out8[3] * wv0.w
                   + out8[4] * wv1.x + out8[5] * wv1.y + out8[6] * wv1.z + out8[7] * wv1.w;
        pdot = row16_sum(pdot);
        if (lane == 0) dots[n] = pdot;
    }
}

// ---------------- h2 = x @ W2 + b2 via MFMA (swapped operands) ----------------
// grid = dim3(8, 782): blockIdx.x = col-tile (fast) -> 8 consecutive blocks
// share the same 64 x-rows (16KB) for L2 reuse.
__global__ void __launch_bounds__(256) gemm_kernel(const unsigned short* __restrict__ x,
                                                   const unsigned short* __restrict__ Wb,
                                                   const float* __restrict__ bias,
                                                   unsigned char* __restrict__ hout) {
    int w = threadIdx.x >> 6, l = threadIdx.x & 63;
    int rb = blockIdx.y * 64 + w * 16;
    int cb = blockIdx.x * 64;
    int lr = l & 15, lq = l >> 4;
    f32x4 acc[4] = {};
    int arow = rb + lr;
    bool rok = arow < N_NODES;
    #pragma unroll
    for (int s = 0; s < 4; s++) {
        s16x8 afr = {};
        if (rok) afr = *reinterpret_cast<const s16x8*>(&x[(size_t)arow * 128 + s * 32 + lq * 8]);
        #pragma unroll
        for (int sub = 0; sub < 4; sub++) {
            s16x8 bfr = *reinterpret_cast<const s16x8*>(
                &Wb[(((size_t)(s * 4 + lq) * 512) + cb + sub * 16 + lr) << 3]);
            acc[sub] = __builtin_amdgcn_mfma_f32_16x16x32_bf16(bfr, afr, acc[sub], 0, 0, 0);
        }
    }
    if (!rok) return;
    #pragma unroll
    for (int sub = 0; sub < 4; sub++) {
        int col0 = cb + sub * 16 + lq * 4;
        float4 bb = *reinterpret_cast<const float4*>(&bias[col0]);
        unsigned int pk = __builtin_amdgcn_cvt_pk_fp8_f32(acc[sub][0] + bb.x,
                                                          acc[sub][1] + bb.y, 0, false);
        pk = __builtin_amdgcn_cvt_pk_fp8_f32(acc[sub][2] + bb.z,
                                             acc[sub][3] + bb.w, pk, true);
        *reinterpret_cast<unsigned int*>(&hout[(size_t)arow * 512 + col0]) = pk;
    }
}

// ---------------- pool over per-node dots + fused final (last block) --------
__global__ void __launch_bounds__(256) pool64_kernel(const float* __restrict__ dots,
                                                     const int* __restrict__ gid,
                                                     float* __restrict__ pool,
                                                     int* __restrict__ done,
                                                     float* __restrict__ out) {
    int wave = (blockIdx.x * blockDim.x + threadIdx.x) >> 6;
    int lane = threadIdx.x & 63;
    int n0 = wave * 64;
    if (n0 < N_NODES) {
        int n = n0 + lane;
        int nc = min(n, N_NODES - 1);
        int g = gid[nc];
        float v = (n < N_NODES) ? dots[n] : 0.f;
        int g0 = __shfl(g, 0);
        bool uni = __all(g == g0);
        if (uni) {
            v += __shfl_xor(v, 1);
            v += __shfl_xor(v, 2);
            v += __shfl_xor(v, 4);
            v += __shfl_xor(v, 8);
            v += __shfl_xor(v, 16);
            v += __shfl_xor(v, 32);
            if (lane == 0) atomicAdd(&pool[g0], v);
        } else {
            if (n < N_NODES) atomicAdd(&pool[g], v);   // rare boundary wave
        }
    }
    __threadfence();
    __syncthreads();
    __shared__ int amlast;
    if (threadIdx.x == 0)
        amlast = (atomicAdd(done, 1) == (int)gridDim.x - 1) ? 1 : 0;
    __syncthreads();
    if (amlast && threadIdx.x < G_GRAPHS) {
        out[threadIdx.x] = atomicAdd(&pool[threadIdx.x], 0.f);
    }
}

extern "C" void kernel_launch(void* const* d_in, const int* in_sizes, int n_in,
                              void* d_out, int out_size, void* d_ws, size_t ws_size,
                              hipStream_t stream) {
    const int* feats = (const int*)d_in[0];
    const int* src   = (const int*)d_in[1];
    const int* dst   = (const int*)d_in[2];
    const int* gids  = (const int*)d_in[3];
    const float* emb  = (const float*)d_in[4];
    const float* W1   = (const float*)d_in[5];
    const float* b1   = (const float*)d_in[6];
    const float* a1   = (const float*)d_in[7];
    const float* W2   = (const float*)d_in[8];
    const float* b2   = (const float*)d_in[9];
    const float* a2   = (const float*)d_in[10];
    const float* wreg = (const float*)d_in[11];
    float* out = (float*)d_out;

    char* ws = (char*)d_ws;
    size_t off = 0;
    auto alloc = [&](size_t bytes) -> void* {
        void* p = ws + off;
        off = (off + bytes + 255) & ~(size_t)255;
        return p;
    };
    // counts + flag + done live in one memset-covered region
    int*   counts  = (int*)alloc((size_t)N_NODES * 4 + 8);
    int*   flag    = counts + N_NODES;       // scanF sync counter
    int*   done    = counts + N_NODES + 1;   // pool64 completion counter
    int*   offsets = (int*)alloc((size_t)(N_NODES + 1) * 4);
    int*   cursor  = (int*)alloc((size_t)N_NODES * 4);
    int*   csr_src = (int*)alloc((size_t)N_EDGES * 4);
    int*   bsum    = (int*)alloc(64 * 4);
    unsigned int*   M1b = (unsigned int*)alloc((size_t)V_VOCAB * HD);     // fp8, 64KB
    unsigned int*   h  = (unsigned int*)alloc((size_t)N_NODES * HD);      // fp8 (layer2)
    unsigned short* x  = (unsigned short*)alloc((size_t)N_NODES * D_DIM * 2);
    unsigned short* Wb = (unsigned short*)alloc((size_t)D_DIM * HD * 2);
    float* dots    = (float*)alloc((size_t)N_NODES * 4);
    float* pool    = (float*)alloc((size_t)G_GRAPHS * 4);

    hipMemsetAsync(counts, 0, (size_t)N_NODES * 4 + 8, stream);

    mega_kernel<<<MEGA_M1_BLOCKS + MEGA_WSZ_BLOCKS + MEGA_HIST_BLOCKS, 256, 0, stream>>>(
        emb, W1, b1, M1b, W2, Wb, dst, counts, pool);
    scanf_kernel<<<64, 256, 0, stream>>>(counts, offsets, cursor, bsum, flag);
    scatter_kernel<<<(N_EDGES + 255) / 256, 256, 0, stream>>>(src, dst, cursor, csr_src);

    gat_kernel<true><<<(N_NODES + 3) / 4, 256, 0, stream>>>(M1b, offsets, csr_src, feats,
                                                            a1, wreg, x, dots);
    gemm_kernel<<<dim3(8, (N_NODES + 63) / 64), 256, 0, stream>>>(x, Wb, b2, (unsigned char*)h);
    gat_kernel<false><<<(N_NODES + 3) / 4, 256, 0, stream>>>(h, offsets, csr_src, feats,
                                                             a2, wreg, x, dots);

    pool64_kernel<<<(N_NODES / 64 + 4) / 4, 256, 0, stream>>>(dots, gids, pool, done, out);
}

// Round 18
// 312.340 us; speedup vs baseline: 1.1736x; 1.0534x over previous
//
#include <hip/hip_runtime.h>
#include <hip/hip_bf16.h>

#define N_NODES 50000
#define N_EDGES 800000
#define G_GRAPHS 64
#define H_HEADS 4
#define D_DIM 128
#define HD 512
#define V_VOCAB 128
#define NEG_SLOPE 0.2f

typedef float f32x2v __attribute__((ext_vector_type(2)));
typedef float f32x4 __attribute__((ext_vector_type(4)));
typedef short s16x8 __attribute__((ext_vector_type(8)));
typedef _Float16 h16x2 __attribute__((ext_vector_type(2)));

static __device__ __forceinline__ unsigned short f2b(float f) {
    union { float f; unsigned int i; } x; x.f = f;
    unsigned int r = x.i + 0x7fffu + ((x.i >> 16) & 1u);
    return (unsigned short)(r >> 16);
}
static __device__ __forceinline__ h16x2 u2h2(unsigned int u) {
    union { unsigned int u; h16x2 h; } c; c.u = u; return c.h;
}
static __device__ __forceinline__ unsigned int h22u(h16x2 h) {
    union { unsigned int u; h16x2 h; } c; c.h = h; return c.u;
}
static __device__ __forceinline__ h16x2 packf2(float lo, float hi) {
    union { __fp16 __attribute__((ext_vector_type(2))) p; h16x2 h; } c;
    c.p = __builtin_amdgcn_cvt_pkrtz(lo, hi);
    return c.h;
}

// unpack 4 fp8 (one dword) -> 2 h16x2
#if __has_builtin(__builtin_amdgcn_cvt_scalef32_pk_f16_fp8)
static __device__ __forceinline__ void fp8x4_to_h16(unsigned int u, h16x2& h0, h16x2& h1) {
    auto r0 = __builtin_amdgcn_cvt_scalef32_pk_f16_fp8((int)u, 1.0f, false);
    auto r1 = __builtin_amdgcn_cvt_scalef32_pk_f16_fp8((int)u, 1.0f, true);
    union { decltype(r0) p; h16x2 h; } c0, c1;
    c0.p = r0; c1.p = r1;
    h0 = c0.h; h1 = c1.h;
}
#else
static __device__ __forceinline__ void fp8x4_to_h16(unsigned int u, h16x2& h0, h16x2& h1) {
    f32x2v lo = __builtin_amdgcn_cvt_pk_f32_fp8(u, false);
    f32x2v hi = __builtin_amdgcn_cvt_pk_f32_fp8(u, true);
    h0 = packf2(lo.x, lo.y);
    h1 = packf2(hi.x, hi.y);
}
#endif

// butterfly-add over the 16-lane row via DPP (VALU pipe, no LDS latency)
template<int CTRL>
static __device__ __forceinline__ float dpp_add(float v) {
    union { float f; int i; } a, b;
    a.f = v;
    b.i = __builtin_amdgcn_mov_dpp(a.i, CTRL, 0xF, 0xF, true);
    return v + b.f;
}
static __device__ __forceinline__ float row16_sum(float p) {
    p = dpp_add<0xB1>(p);    // quad_perm [1,0,3,2]  : xor 1
    p = dpp_add<0x4E>(p);    // quad_perm [2,3,0,1]  : xor 2
    p = dpp_add<0x141>(p);   // ROW_HALF_MIRROR      : cross-quad in 8
    p = dpp_add<0x140>(p);   // ROW_MIRROR           : cross-8 in 16
    return p;
}

// ---- mega: M1b = fp8(emb@W1 + b1) (128x512, 64KB) | Wb swizzle | hist | pool0
#define MEGA_M1_BLOCKS   64
#define MEGA_WSZ_BLOCKS  256
#define MEGA_HIST_BLOCKS ((N_EDGES + 255) / 256)   // 3125
__global__ void __launch_bounds__(256) mega_kernel(const float* __restrict__ emb,
                                                   const float* __restrict__ W1,
                                                   const float* __restrict__ b1,
                                                   unsigned int* __restrict__ M1b,
                                                   const float* __restrict__ W2,
                                                   unsigned short* __restrict__ Wb,
                                                   const int* __restrict__ dst,
                                                   int* __restrict__ counts,
                                                   float* __restrict__ pool) {
    int b = blockIdx.x;
    if (b < MEGA_M1_BLOCKS) {
        int idx = b * 256 + threadIdx.x;     // 16384 threads, 4 cols each
        int v = idx >> 7, c0 = (idx & 127) * 4;
        float acc[4] = {b1[c0], b1[c0 + 1], b1[c0 + 2], b1[c0 + 3]};
        for (int k = 0; k < 128; k++) {
            float e = emb[v * 128 + k];
            #pragma unroll
            for (int j = 0; j < 4; j++) acc[j] = fmaf(e, W1[k * 512 + c0 + j], acc[j]);
        }
        unsigned int pk = __builtin_amdgcn_cvt_pk_fp8_f32(acc[0], acc[1], 0, false);
        pk = __builtin_amdgcn_cvt_pk_fp8_f32(acc[2], acc[3], pk, true);
        M1b[idx] = pk;
    } else if (b < MEGA_M1_BLOCKS + MEGA_WSZ_BLOCKS) {
        int idx = (b - MEGA_M1_BLOCKS) * 256 + threadIdx.x;   // 65536
        int j = idx & 7, c = (idx >> 3) & 511, qq = idx >> 12;
        Wb[idx] = f2b(W2[(qq * 8 + j) * 512 + c]);
    } else {
        int hb = b - MEGA_M1_BLOCKS - MEGA_WSZ_BLOCKS;
        if (hb == 0 && threadIdx.x < G_GRAPHS) pool[threadIdx.x] = 0.f;
        int i = hb * 256 + threadIdx.x;
        if (i < N_EDGES) atomicAdd(&counts[dst[i]], 1);
    }
}

// ---- Wtab[fd][fs][head] = softmax-weight for layer 1 (65536 floats, 256KB)
// Layer-1 logit depends only on (feats[s], feats[d]): 128x128x4 distinct values.
__global__ void __launch_bounds__(256) wtab_kernel(const unsigned int* __restrict__ M1b,
                                                   const float* __restrict__ a,
                                                   float* __restrict__ Wtab) {
    int wid = threadIdx.x >> 6, lane = threadIdx.x & 63;
    int pid = blockIdx.x * 4 + wid;          // 0..16383 = fd*128+fs
    int fd = pid >> 7, fs = pid & 127;
    int voff = lane * 2;

    h16x2 a06[4], a04[4], hd2[4], hs[4];
    float4 av0 = *reinterpret_cast<const float4*>(&a[lane * 8]);
    float4 av1 = *reinterpret_cast<const float4*>(&a[lane * 8 + 4]);
    float aa[8] = {av0.x, av0.y, av0.z, av0.w, av1.x, av1.y, av1.z, av1.w};
    const float L2E = 1.4426950408889634f;
    #pragma unroll
    for (int k = 0; k < 4; k++) {
        a06[k][0] = (_Float16)(aa[2*k]   * (0.6f * L2E));
        a06[k][1] = (_Float16)(aa[2*k+1] * (0.6f * L2E));
        a04[k][0] = (_Float16)(aa[2*k]   * (0.4f * L2E));
        a04[k][1] = (_Float16)(aa[2*k+1] * (0.4f * L2E));
    }
    uint2 hv = *reinterpret_cast<const uint2*>(&M1b[(unsigned)fd * 128u + voff]);
    fp8x4_to_h16(hv.x, hd2[0], hd2[1]);
    fp8x4_to_h16(hv.y, hd2[2], hd2[3]);
    uint2 sv = *reinterpret_cast<const uint2*>(&M1b[(unsigned)fs * 128u + voff]);
    fp8x4_to_h16(sv.x, hs[0], hs[1]);
    fp8x4_to_h16(sv.y, hs[2], hs[3]);

    float p = 0.f;
    #pragma unroll
    for (int k = 0; k < 4; k++) {
        h16x2 t2 = hs[k] + hd2[k];
        h16x2 at2 = u2h2(h22u(t2) & 0x7FFF7FFFu);
        p = __builtin_amdgcn_fdot2(t2, a06[k], p, false);
        p = __builtin_amdgcn_fdot2(at2, a04[k], p, false);
    }
    p = row16_sum(p);
    const float C1 = 0.69314718f, C2 = 0.24022651f, C3 = 0.05550411f;
    float w = fmaf(p, fmaf(p, fmaf(p, C3, C2), C1), 1.f);
    if ((lane & 15) == 0) Wtab[pid * 4 + (lane >> 4)] = w;
}

// ---------------- fused CSR scan (device-scope flag sync, 64 blocks) --------
__global__ void __launch_bounds__(256) scanf_kernel(const int* __restrict__ counts,
                                                    int* __restrict__ offsets,
                                                    int* __restrict__ cursor,
                                                    int* __restrict__ bsum,
                                                    int* __restrict__ flag) {
    __shared__ int buf[256];
    __shared__ int sbase;
    int t = threadIdx.x, b = blockIdx.x;
    int i0 = (b * 256 + t) * 4;
    int v[4], c[4], s = 0;
    #pragma unroll
    for (int j = 0; j < 4; j++) {
        int idx = i0 + j;
        v[j] = (idx < N_NODES) ? counts[idx] : 0;
        s += v[j];
        c[j] = s;
    }
    buf[t] = s;
    __syncthreads();
    for (int off = 1; off < 256; off <<= 1) {
        int add = (t >= off) ? buf[t - off] : 0;
        __syncthreads();
        buf[t] += add;
        __syncthreads();
    }
    int ebase = (t > 0) ? buf[t - 1] : 0;
    if (t == 0) {
        bsum[b] = buf[255];
        __threadfence();
        atomicAdd(flag, 1);
        while (atomicAdd(flag, 0) < 64) __builtin_amdgcn_s_sleep(8);
    }
    __syncthreads();
    if (t < 64) {
        int vv = (t < b) ? atomicAdd(&bsum[t], 0) : 0;
        #pragma unroll
        for (int off = 1; off < 64; off <<= 1) vv += __shfl_xor(vv, off);
        if (t == 0) sbase = vv;
    }
    __syncthreads();
    int base = sbase;
    #pragma unroll
    for (int j = 0; j < 4; j++) {
        int idx = i0 + j;
        if (idx < N_NODES) {
            int e = base + ebase + c[j];
            offsets[idx + 1] = e;
            cursor[idx] = e - v[j];
        }
    }
    if (b == 0 && t == 0) offsets[0] = 0;
}

// ---------------- scatter ----------------
__global__ void scatter_kernel(const int* __restrict__ src, const int* __restrict__ dst,
                               int* __restrict__ cursor, int* __restrict__ csr_src) {
    int i = blockIdx.x * blockDim.x + threadIdx.x;
    if (i < N_EDGES) {
        int d = dst[i];
        int pos = atomicAdd(&cursor[d], 1);
        csr_src[pos] = src[i];
    }
}

// ---------------- GATv2 layer ----------------
// LAYER1: per-edge weight looked up from Wtab (no per-edge dot/exp at all);
//         rows from 64KB M1b table; writes x.
// LAYER2: frozen round-15 path; writes dot(x_row,wreg) per node.
template<bool LAYER1>
__global__ void __launch_bounds__(256) gat_kernel(const unsigned int* __restrict__ h,
                                                  const int* __restrict__ offsets,
                                                  const int* __restrict__ csr_src,
                                                  const int* __restrict__ feats,
                                                  const float* __restrict__ a,
                                                  const float* __restrict__ wreg,
                                                  const float* __restrict__ Wtab,
                                                  unsigned short* __restrict__ x,
                                                  float* __restrict__ dots) {
    int wid = threadIdx.x >> 6;
    int lane = threadIdx.x & 63;
    int n = blockIdx.x * 4 + wid;
    if (n >= N_NODES) return;
    n = __builtin_amdgcn_readfirstlane(n);
    int row_s = __builtin_amdgcn_readfirstlane(offsets[n]);
    int row_e = __builtin_amdgcn_readfirstlane(offsets[n + 1]);
    int cnt = row_e - row_s;
    int voff = lane * 2;                 // per-lane dword offset into a row

    if constexpr (LAYER1) {
        int fd = __builtin_amdgcn_readfirstlane(feats[n]);
        const float* wrow = &Wtab[fd * 512];    // [fs][head] for this dst
        int woff = lane >> 4;                    // head
        h16x2 acc2[4];
        #pragma unroll
        for (int k = 0; k < 4; k++) { acc2[k][0] = (_Float16)0.f; acc2[k][1] = (_Float16)0.f; }
        float den = 0.f;

        auto ld1 = [&](int ii, uint2& row, float& wv) {
            int e = __builtin_amdgcn_readfirstlane(csr_src[row_s + ii]);
            int fs = __builtin_amdgcn_readfirstlane(feats[e]);
            row = *reinterpret_cast<const uint2*>(&h[(unsigned)fs * 128u + voff]);
            wv = wrow[fs * 4 + woff];
        };

        uint2 rA = make_uint2(0, 0), rB = make_uint2(0, 0);
        float wA = 0.f, wB = 0.f;
        if (cnt > 0) ld1(0, rA, wA);
        if (cnt > 1) ld1(1, rB, wB);

        auto proc = [&](uint2 sv, float wv) {
            h16x2 hs[4];
            fp8x4_to_h16(sv.x, hs[0], hs[1]);
            fp8x4_to_h16(sv.y, hs[2], hs[3]);
            den += wv;
            h16x2 w2 = packf2(wv, wv);
            #pragma unroll
            for (int k = 0; k < 4; k++) acc2[k] = w2 * hs[k] + acc2[k];
        };

        for (int i = 0; i < cnt; i += 2) {
            { uint2 c = rA; float wc = wA; ld1(min(i + 2, cnt - 1), rA, wA); proc(c, wc); }
            if (i + 1 < cnt) { uint2 c = rB; float wc = wB; ld1(min(i + 3, cnt - 1), rB, wB); proc(c, wc); }
        }

        float inv = (den > 0.f) ? 0.25f / den : 0.f;
        float out8[8];
        #pragma unroll
        for (int j = 0; j < 8; j++) {
            float r = (float)acc2[j >> 1][j & 1] * inv;
            r += __shfl_xor(r, 16);
            r += __shfl_xor(r, 32);
            out8[j] = r;
        }
        if (lane < 16) {
            union { unsigned short u[8]; uint4 v; } o;
            #pragma unroll
            for (int j = 0; j < 8; j++) o.u[j] = f2b(out8[j]);
            *reinterpret_cast<uint4*>(&x[(unsigned)n * 128u + lane * 8]) = o.v;
        }
        return;
    } else {
        h16x2 hd2[4], a06[4], a04[4], acc2[4];
        float pd;
        {
            uint2 hv = *reinterpret_cast<const uint2*>(&h[(unsigned)n * 128u + voff]);
            fp8x4_to_h16(hv.x, hd2[0], hd2[1]);
            fp8x4_to_h16(hv.y, hd2[2], hd2[3]);
            float4 av0 = *reinterpret_cast<const float4*>(&a[lane * 8]);
            float4 av1 = *reinterpret_cast<const float4*>(&a[lane * 8 + 4]);
            float aa[8] = {av0.x, av0.y, av0.z, av0.w, av1.x, av1.y, av1.z, av1.w};
            const float L2E = 1.4426950408889634f;
            #pragma unroll
            for (int k = 0; k < 4; k++) {
                a06[k][0] = (_Float16)(aa[2*k]   * (0.6f * L2E));
                a06[k][1] = (_Float16)(aa[2*k+1] * (0.6f * L2E));
                a04[k][0] = (_Float16)(aa[2*k]   * (0.4f * L2E));
                a04[k][1] = (_Float16)(aa[2*k+1] * (0.4f * L2E));
                acc2[k][0] = (_Float16)0.f; acc2[k][1] = (_Float16)0.f;
            }
            float s = 0.f;
            #pragma unroll
            for (int k = 0; k < 4; k++) s = __builtin_amdgcn_fdot2(hd2[k], a06[k], s, false);
            pd = row16_sum(s);
        }

        auto ld = [&](int ii) {
            int s = __builtin_amdgcn_readfirstlane(csr_src[row_s + ii]);
            return *reinterpret_cast<const uint2*>(&h[(unsigned)s * 128u + voff]);
        };

        float den = 0.f;
        uint2 rA = make_uint2(0, 0), rB = make_uint2(0, 0);
        if (cnt > 0) rA = ld(0);
        if (cnt > 1) rB = ld(1);

        const float C1 = 0.69314718f, C2 = 0.24022651f, C3 = 0.05550411f;

        auto process = [&](uint2 sv) {
            h16x2 hs[4];
            fp8x4_to_h16(sv.x, hs[0], hs[1]);
            fp8x4_to_h16(sv.y, hs[2], hs[3]);
            float p0 = 0.f, p1 = 0.f;
            #pragma unroll
            for (int k = 0; k < 2; k++) {
                h16x2 t2 = hs[k] + hd2[k];
                h16x2 at2 = u2h2(h22u(t2) & 0x7FFF7FFFu);
                p0 = __builtin_amdgcn_fdot2(hs[k], a06[k], p0, false);
                p0 = __builtin_amdgcn_fdot2(at2, a04[k], p0, false);
            }
            #pragma unroll
            for (int k = 2; k < 4; k++) {
                h16x2 t2 = hs[k] + hd2[k];
                h16x2 at2 = u2h2(h22u(t2) & 0x7FFF7FFFu);
                p1 = __builtin_amdgcn_fdot2(hs[k], a06[k], p1, false);
                p1 = __builtin_amdgcn_fdot2(at2, a04[k], p1, false);
            }
            float p = row16_sum(p0 + p1) + pd;
            float w = fmaf(p, fmaf(p, fmaf(p, C3, C2), C1), 1.f);
            den += w;
            h16x2 w2 = packf2(w, w);
            #pragma unroll
            for (int k = 0; k < 4; k++) acc2[k] = w2 * hs[k] + acc2[k];
        };

        for (int i = 0; i < cnt; i += 2) {
            { uint2 cur = rA; rA = ld(min(i + 2, cnt - 1)); process(cur); }
            if (i + 1 < cnt) { uint2 cur = rB; rB = ld(min(i + 3, cnt - 1)); process(cur); }
        }

        float inv = (den > 0.f) ? 0.25f / den : 0.f;
        float out8[8];
        #pragma unroll
        for (int j = 0; j < 8; j++) {
            float r = (float)acc2[j >> 1][j & 1] * inv;
            r += __shfl_xor(r, 16);
            r += __shfl_xor(r, 32);
            out8[j] = r;
        }
        int d0 = (lane & 15) * 8;
        float4 wv0 = *reinterpret_cast<const float4*>(&wreg[d0]);
        float4 wv1 = *reinterpret_cast<const float4*>(&wreg[d0 + 4]);
        float pdot = out8[0] * wv0.x + out8[1] * wv0.y + out8[2] * wv0.z + out8[3] * wv0.w
                   + out8[4] * wv1.x + out8[5] * wv1.y + out8[6] * wv1.z + out8[7] * wv1.w;
        pdot = row16_sum(pdot);
        if (lane == 0) dots[n] = pdot;
    }
}

// ---------------- h2 = x @ W2 + b2 via MFMA (swapped operands) ----------------
__global__ void __launch_bounds__(256) gemm_kernel(const unsigned short* __restrict__ x,
                                                   const unsigned short* __restrict__ Wb,
                                                   const float* __restrict__ bias,
                                                   unsigned char* __restrict__ hout) {
    int w = threadIdx.x >> 6, l = threadIdx.x & 63;
    int rb = blockIdx.y * 64 + w * 16;
    int cb = blockIdx.x * 64;
    int lr = l & 15, lq = l >> 4;
    f32x4 acc[4] = {};
    int arow = rb + lr;
    bool rok = arow < N_NODES;
    #pragma unroll
    for (int s = 0; s < 4; s++) {
        s16x8 afr = {};
        if (rok) afr = *reinterpret_cast<const s16x8*>(&x[(size_t)arow * 128 + s * 32 + lq * 8]);
        #pragma unroll
        for (int sub = 0; sub < 4; sub++) {
            s16x8 bfr = *reinterpret_cast<const s16x8*>(
                &Wb[(((size_t)(s * 4 + lq) * 512) + cb + sub * 16 + lr) << 3]);
            acc[sub] = __builtin_amdgcn_mfma_f32_16x16x32_bf16(bfr, afr, acc[sub], 0, 0, 0);
        }
    }
    if (!rok) return;
    #pragma unroll
    for (int sub = 0; sub < 4; sub++) {
        int col0 = cb + sub * 16 + lq * 4;
        float4 bb = *reinterpret_cast<const float4*>(&bias[col0]);
        unsigned int pk = __builtin_amdgcn_cvt_pk_fp8_f32(acc[sub][0] + bb.x,
                                                          acc[sub][1] + bb.y, 0, false);
        pk = __builtin_amdgcn_cvt_pk_fp8_f32(acc[sub][2] + bb.z,
                                             acc[sub][3] + bb.w, pk, true);
        *reinterpret_cast<unsigned int*>(&hout[(size_t)arow * 512 + col0]) = pk;
    }
}

// ---------------- pool over per-node dots + fused final (last block) --------
__global__ void __launch_bounds__(256) pool64_kernel(const float* __restrict__ dots,
                                                     const int* __restrict__ gid,
                                                     float* __restrict__ pool,
                                                     int* __restrict__ done,
                                                     float* __restrict__ out) {
    int wave = (blockIdx.x * blockDim.x + threadIdx.x) >> 6;
    int lane = threadIdx.x & 63;
    int n0 = wave * 64;
    if (n0 < N_NODES) {
        int n = n0 + lane;
        int nc = min(n, N_NODES - 1);
        int g = gid[nc];
        float v = (n < N_NODES) ? dots[n] : 0.f;
        int g0 = __shfl(g, 0);
        bool uni = __all(g == g0);
        if (uni) {
            v += __shfl_xor(v, 1);
            v += __shfl_xor(v, 2);
            v += __shfl_xor(v, 4);
            v += __shfl_xor(v, 8);
            v += __shfl_xor(v, 16);
            v += __shfl_xor(v, 32);
            if (lane == 0) atomicAdd(&pool[g0], v);
        } else {
            if (n < N_NODES) atomicAdd(&pool[g], v);   // rare boundary wave
        }
    }
    __threadfence();
    __syncthreads();
    __shared__ int amlast;
    if (threadIdx.x == 0)
        amlast = (atomicAdd(done, 1) == (int)gridDim.x - 1) ? 1 : 0;
    __syncthreads();
    if (amlast && threadIdx.x < G_GRAPHS) {
        out[threadIdx.x] = atomicAdd(&pool[threadIdx.x], 0.f);
    }
}

extern "C" void kernel_launch(void* const* d_in, const int* in_sizes, int n_in,
                              void* d_out, int out_size, void* d_ws, size_t ws_size,
                              hipStream_t stream) {
    const int* feats = (const int*)d_in[0];
    const int* src   = (const int*)d_in[1];
    const int* dst   = (const int*)d_in[2];
    const int* gids  = (const int*)d_in[3];
    const float* emb  = (const float*)d_in[4];
    const float* W1   = (const float*)d_in[5];
    const float* b1   = (const float*)d_in[6];
    const float* a1   = (const float*)d_in[7];
    const float* W2   = (const float*)d_in[8];
    const float* b2   = (const float*)d_in[9];
    const float* a2   = (const float*)d_in[10];
    const float* wreg = (const float*)d_in[11];
    float* out = (float*)d_out;

    char* ws = (char*)d_ws;
    size_t off = 0;
    auto alloc = [&](size_t bytes) -> void* {
        void* p = ws + off;
        off = (off + bytes + 255) & ~(size_t)255;
        return p;
    };
    // counts + flag + done live in one memset-covered region
    int*   counts  = (int*)alloc((size_t)N_NODES * 4 + 8);
    int*   flag    = counts + N_NODES;       // scanF sync counter
    int*   done    = counts + N_NODES + 1;   // pool64 completion counter
    int*   offsets = (int*)alloc((size_t)(N_NODES + 1) * 4);
    int*   cursor  = (int*)alloc((size_t)N_NODES * 4);
    int*   csr_src = (int*)alloc((size_t)N_EDGES * 4);
    int*   bsum    = (int*)alloc(64 * 4);
    unsigned int*   M1b = (unsigned int*)alloc((size_t)V_VOCAB * HD);     // fp8, 64KB
    unsigned int*   h  = (unsigned int*)alloc((size_t)N_NODES * HD);      // fp8 (layer2)
    unsigned short* x  = (unsigned short*)alloc((size_t)N_NODES * D_DIM * 2);
    unsigned short* Wb = (unsigned short*)alloc((size_t)D_DIM * HD * 2);
    float* Wtab    = (float*)alloc((size_t)V_VOCAB * V_VOCAB * H_HEADS * 4); // 256KB
    float* dots    = (float*)alloc((size_t)N_NODES * 4);
    float* pool    = (float*)alloc((size_t)G_GRAPHS * 4);

    hipMemsetAsync(counts, 0, (size_t)N_NODES * 4 + 8, stream);

    mega_kernel<<<MEGA_M1_BLOCKS + MEGA_WSZ_BLOCKS + MEGA_HIST_BLOCKS, 256, 0, stream>>>(
        emb, W1, b1, M1b, W2, Wb, dst, counts, pool);
    wtab_kernel<<<(V_VOCAB * V_VOCAB) / 4, 256, 0, stream>>>(M1b, a1, Wtab);
    scanf_kernel<<<64, 256, 0, stream>>>(counts, offsets, cursor, bsum, flag);
    scatter_kernel<<<(N_EDGES + 255) / 256, 256, 0, stream>>>(src, dst, cursor, csr_src);

    gat_kernel<true><<<(N_NODES + 3) / 4, 256, 0, stream>>>(M1b, offsets, csr_src, feats,
                                                            a1, wreg, Wtab, x, dots);
    gemm_kernel<<<dim3(8, (N_NODES + 63) / 64), 256, 0, stream>>>(x, Wb, b2, (unsigned char*)h);
    gat_kernel<false><<<(N_NODES + 3) / 4, 256, 0, stream>>>(h, offsets, csr_src, feats,
                                                             a2, wreg, Wtab, x, dots);

    pool64_kernel<<<(N_NODES / 64 + 4) / 4, 256, 0, stream>>>(dots, gids, pool, done, out);
}

// Round 19
// 307.636 us; speedup vs baseline: 1.1915x; 1.0153x over previous
//
#include <hip/hip_runtime.h>
#include <hip/hip_bf16.h>

#define N_NODES 50000
#define N_EDGES 800000
#define G_GRAPHS 64
#define H_HEADS 4
#define D_DIM 128
#define HD 512
#define V_VOCAB 128
#define NEG_SLOPE 0.2f

typedef float f32x2v __attribute__((ext_vector_type(2)));
typedef float f32x4 __attribute__((ext_vector_type(4)));
typedef short s16x8 __attribute__((ext_vector_type(8)));
typedef _Float16 h16x2 __attribute__((ext_vector_type(2)));

static __device__ __forceinline__ unsigned short f2b(float f) {
    union { float f; unsigned int i; } x; x.f = f;
    unsigned int r = x.i + 0x7fffu + ((x.i >> 16) & 1u);
    return (unsigned short)(r >> 16);
}
static __device__ __forceinline__ h16x2 u2h2(unsigned int u) {
    union { unsigned int u; h16x2 h; } c; c.u = u; return c.h;
}
static __device__ __forceinline__ unsigned int h22u(h16x2 h) {
    union { unsigned int u; h16x2 h; } c; c.h = h; return c.u;
}
static __device__ __forceinline__ h16x2 packf2(float lo, float hi) {
    union { __fp16 __attribute__((ext_vector_type(2))) p; h16x2 h; } c;
    c.p = __builtin_amdgcn_cvt_pkrtz(lo, hi);
    return c.h;
}

// unpack 4 fp8 (one dword) -> 2 h16x2
#if __has_builtin(__builtin_amdgcn_cvt_scalef32_pk_f16_fp8)
static __device__ __forceinline__ void fp8x4_to_h16(unsigned int u, h16x2& h0, h16x2& h1) {
    auto r0 = __builtin_amdgcn_cvt_scalef32_pk_f16_fp8((int)u, 1.0f, false);
    auto r1 = __builtin_amdgcn_cvt_scalef32_pk_f16_fp8((int)u, 1.0f, true);
    union { decltype(r0) p; h16x2 h; } c0, c1;
    c0.p = r0; c1.p = r1;
    h0 = c0.h; h1 = c1.h;
}
#else
static __device__ __forceinline__ void fp8x4_to_h16(unsigned int u, h16x2& h0, h16x2& h1) {
    f32x2v lo = __builtin_amdgcn_cvt_pk_f32_fp8(u, false);
    f32x2v hi = __builtin_amdgcn_cvt_pk_f32_fp8(u, true);
    h0 = packf2(lo.x, lo.y);
    h1 = packf2(hi.x, hi.y);
}
#endif

// butterfly-add over the 16-lane row via DPP (VALU pipe, no LDS latency)
template<int CTRL>
static __device__ __forceinline__ float dpp_add(float v) {
    union { float f; int i; } a, b;
    a.f = v;
    b.i = __builtin_amdgcn_mov_dpp(a.i, CTRL, 0xF, 0xF, true);
    return v + b.f;
}
static __device__ __forceinline__ float row16_sum(float p) {
    p = dpp_add<0xB1>(p);    // quad_perm [1,0,3,2]  : xor 1
    p = dpp_add<0x4E>(p);    // quad_perm [2,3,0,1]  : xor 2
    p = dpp_add<0x141>(p);   // ROW_HALF_MIRROR      : cross-quad in 8
    p = dpp_add<0x140>(p);   // ROW_MIRROR           : cross-8 in 16
    return p;
}

// ---- mega: M1b = fp8(emb@W1 + b1) (128x512, 64KB) | Wb swizzle | hist | pool0
#define MEGA_M1_BLOCKS   64
#define MEGA_WSZ_BLOCKS  256
#define MEGA_HIST_BLOCKS ((N_EDGES + 255) / 256)   // 3125
__global__ void __launch_bounds__(256) mega_kernel(const float* __restrict__ emb,
                                                   const float* __restrict__ W1,
                                                   const float* __restrict__ b1,
                                                   unsigned int* __restrict__ M1b,
                                                   const float* __restrict__ W2,
                                                   unsigned short* __restrict__ Wb,
                                                   const int* __restrict__ dst,
                                                   int* __restrict__ counts,
                                                   float* __restrict__ pool) {
    int b = blockIdx.x;
    if (b < MEGA_M1_BLOCKS) {
        int idx = b * 256 + threadIdx.x;     // 16384 threads, 4 cols each
        int v = idx >> 7, c0 = (idx & 127) * 4;
        float acc[4] = {b1[c0], b1[c0 + 1], b1[c0 + 2], b1[c0 + 3]};
        for (int k = 0; k < 128; k++) {
            float e = emb[v * 128 + k];
            #pragma unroll
            for (int j = 0; j < 4; j++) acc[j] = fmaf(e, W1[k * 512 + c0 + j], acc[j]);
        }
        unsigned int pk = __builtin_amdgcn_cvt_pk_fp8_f32(acc[0], acc[1], 0, false);
        pk = __builtin_amdgcn_cvt_pk_fp8_f32(acc[2], acc[3], pk, true);
        M1b[idx] = pk;
    } else if (b < MEGA_M1_BLOCKS + MEGA_WSZ_BLOCKS) {
        int idx = (b - MEGA_M1_BLOCKS) * 256 + threadIdx.x;   // 65536
        int j = idx & 7, c = (idx >> 3) & 511, qq = idx >> 12;
        Wb[idx] = f2b(W2[(qq * 8 + j) * 512 + c]);
    } else {
        int hb = b - MEGA_M1_BLOCKS - MEGA_WSZ_BLOCKS;
        if (hb == 0 && threadIdx.x < G_GRAPHS) pool[threadIdx.x] = 0.f;
        int i = hb * 256 + threadIdx.x;
        if (i < N_EDGES) atomicAdd(&counts[dst[i]], 1);
    }
}

// ---- Wtab[fd][fs][head] = softmax-weight for layer 1 (65536 floats, 256KB)
__global__ void __launch_bounds__(256) wtab_kernel(const unsigned int* __restrict__ M1b,
                                                   const float* __restrict__ a,
                                                   float* __restrict__ Wtab) {
    int wid = threadIdx.x >> 6, lane = threadIdx.x & 63;
    int pid = blockIdx.x * 4 + wid;          // 0..16383 = fd*128+fs
    int fd = pid >> 7, fs = pid & 127;
    int voff = lane * 2;

    h16x2 a06[4], a04[4], hd2[4], hs[4];
    float4 av0 = *reinterpret_cast<const float4*>(&a[lane * 8]);
    float4 av1 = *reinterpret_cast<const float4*>(&a[lane * 8 + 4]);
    float aa[8] = {av0.x, av0.y, av0.z, av0.w, av1.x, av1.y, av1.z, av1.w};
    const float L2E = 1.4426950408889634f;
    #pragma unroll
    for (int k = 0; k < 4; k++) {
        a06[k][0] = (_Float16)(aa[2*k]   * (0.6f * L2E));
        a06[k][1] = (_Float16)(aa[2*k+1] * (0.6f * L2E));
        a04[k][0] = (_Float16)(aa[2*k]   * (0.4f * L2E));
        a04[k][1] = (_Float16)(aa[2*k+1] * (0.4f * L2E));
    }
    uint2 hv = *reinterpret_cast<const uint2*>(&M1b[(unsigned)fd * 128u + voff]);
    fp8x4_to_h16(hv.x, hd2[0], hd2[1]);
    fp8x4_to_h16(hv.y, hd2[2], hd2[3]);
    uint2 sv = *reinterpret_cast<const uint2*>(&M1b[(unsigned)fs * 128u + voff]);
    fp8x4_to_h16(sv.x, hs[0], hs[1]);
    fp8x4_to_h16(sv.y, hs[2], hs[3]);

    float p = 0.f;
    #pragma unroll
    for (int k = 0; k < 4; k++) {
        h16x2 t2 = hs[k] + hd2[k];
        h16x2 at2 = u2h2(h22u(t2) & 0x7FFF7FFFu);
        p = __builtin_amdgcn_fdot2(t2, a06[k], p, false);
        p = __builtin_amdgcn_fdot2(at2, a04[k], p, false);
    }
    p = row16_sum(p);
    const float C1 = 0.69314718f, C2 = 0.24022651f, C3 = 0.05550411f;
    float w = fmaf(p, fmaf(p, fmaf(p, C3, C2), C1), 1.f);
    if ((lane & 15) == 0) Wtab[pid * 4 + (lane >> 4)] = w;
}

// ---------------- fused CSR scan (device-scope flag sync, 64 blocks) --------
__global__ void __launch_bounds__(256) scanf_kernel(const int* __restrict__ counts,
                                                    int* __restrict__ offsets,
                                                    int* __restrict__ cursor,
                                                    int* __restrict__ bsum,
                                                    int* __restrict__ flag) {
    __shared__ int buf[256];
    __shared__ int sbase;
    int t = threadIdx.x, b = blockIdx.x;
    int i0 = (b * 256 + t) * 4;
    int v[4], c[4], s = 0;
    #pragma unroll
    for (int j = 0; j < 4; j++) {
        int idx = i0 + j;
        v[j] = (idx < N_NODES) ? counts[idx] : 0;
        s += v[j];
        c[j] = s;
    }
    buf[t] = s;
    __syncthreads();
    for (int off = 1; off < 256; off <<= 1) {
        int add = (t >= off) ? buf[t - off] : 0;
        __syncthreads();
        buf[t] += add;
        __syncthreads();
    }
    int ebase = (t > 0) ? buf[t - 1] : 0;
    if (t == 0) {
        bsum[b] = buf[255];
        __threadfence();
        atomicAdd(flag, 1);
        while (atomicAdd(flag, 0) < 64) __builtin_amdgcn_s_sleep(8);
    }
    __syncthreads();
    if (t < 64) {
        int vv = (t < b) ? atomicAdd(&bsum[t], 0) : 0;
        #pragma unroll
        for (int off = 1; off < 64; off <<= 1) vv += __shfl_xor(vv, off);
        if (t == 0) sbase = vv;
    }
    __syncthreads();
    int base = sbase;
    #pragma unroll
    for (int j = 0; j < 4; j++) {
        int idx = i0 + j;
        if (idx < N_NODES) {
            int e = base + ebase + c[j];
            offsets[idx + 1] = e;
            cursor[idx] = e - v[j];
        }
    }
    if (b == 0 && t == 0) offsets[0] = 0;
}

// ---------------- scatter ----------------
__global__ void scatter_kernel(const int* __restrict__ src, const int* __restrict__ dst,
                               int* __restrict__ cursor, int* __restrict__ csr_src) {
    int i = blockIdx.x * blockDim.x + threadIdx.x;
    if (i < N_EDGES) {
        int d = dst[i];
        int pos = atomicAdd(&cursor[d], 1);
        csr_src[pos] = src[i];
    }
}

// ---------------- GATv2 layer ----------------
// Wave-wide index preload: lane i loads csr_src[row_s+i] (and feats[] for
// LAYER1) in ONE vector load per 64-edge chunk; per-edge index then comes from
// v_readlane (uniform i -> SGPR, feeds saddr row load). Kills the per-edge
// dependent load chain. 2-deep row prefetch kept (deeper regressed, r13).
template<bool LAYER1>
__global__ void __launch_bounds__(256) gat_kernel(const unsigned int* __restrict__ h,
                                                  const int* __restrict__ offsets,
                                                  const int* __restrict__ csr_src,
                                                  const int* __restrict__ feats,
                                                  const float* __restrict__ a,
                                                  const float* __restrict__ wreg,
                                                  const float* __restrict__ Wtab,
                                                  unsigned short* __restrict__ x,
                                                  float* __restrict__ dots) {
    int wid = threadIdx.x >> 6;
    int lane = threadIdx.x & 63;
    int n = blockIdx.x * 4 + wid;
    if (n >= N_NODES) return;
    n = __builtin_amdgcn_readfirstlane(n);
    int row_s = __builtin_amdgcn_readfirstlane(offsets[n]);
    int row_e = __builtin_amdgcn_readfirstlane(offsets[n + 1]);
    int cnt = row_e - row_s;
    int voff = lane * 2;                 // per-lane dword offset into a row

    auto ldrow = [&](int s) {
        return *reinterpret_cast<const uint2*>(&h[(unsigned)s * 128u + voff]);
    };

    if constexpr (LAYER1) {
        int fd = __builtin_amdgcn_readfirstlane(feats[n]);
        const float* wrow = &Wtab[fd * 512];    // [fs][head] for this dst
        int woff = lane >> 4;                    // head
        h16x2 acc2[4];
        #pragma unroll
        for (int k = 0; k < 4; k++) { acc2[k][0] = (_Float16)0.f; acc2[k][1] = (_Float16)0.f; }
        float den = 0.f;

        auto proc = [&](uint2 sv, float wv) {
            h16x2 hs[4];
            fp8x4_to_h16(sv.x, hs[0], hs[1]);
            fp8x4_to_h16(sv.y, hs[2], hs[3]);
            den += wv;
            h16x2 w2 = packf2(wv, wv);
            #pragma unroll
            for (int k = 0; k < 4; k++) acc2[k] = w2 * hs[k] + acc2[k];
        };

        for (int base = 0; base < cnt; base += 64) {
            int m = min(64, cnt - base);
            // wave-wide index preload: lane i -> fs of edge base+i
            int ev = 0;
            if (lane < m) ev = feats[csr_src[row_s + base + lane]];
            int s0 = __builtin_amdgcn_readlane(ev, 0);
            int s1 = __builtin_amdgcn_readlane(ev, m > 1 ? 1 : 0);
            uint2 rA = ldrow(s0), rB = ldrow(s1);
            float wA = wrow[s0 * 4 + woff], wB = wrow[s1 * 4 + woff];
            for (int i = 0; i < m; i += 2) {
                {
                    uint2 c = rA; float wc = wA;
                    int sn = __builtin_amdgcn_readlane(ev, min(i + 2, m - 1));
                    rA = ldrow(sn); wA = wrow[sn * 4 + woff];
                    proc(c, wc);
                }
                if (i + 1 < m) {
                    uint2 c = rB; float wc = wB;
                    int sn = __builtin_amdgcn_readlane(ev, min(i + 3, m - 1));
                    rB = ldrow(sn); wB = wrow[sn * 4 + woff];
                    proc(c, wc);
                }
            }
        }

        float inv = (den > 0.f) ? 0.25f / den : 0.f;
        float out8[8];
        #pragma unroll
        for (int j = 0; j < 8; j++) {
            float r = (float)acc2[j >> 1][j & 1] * inv;
            r += __shfl_xor(r, 16);
            r += __shfl_xor(r, 32);
            out8[j] = r;
        }
        if (lane < 16) {
            union { unsigned short u[8]; uint4 v; } o;
            #pragma unroll
            for (int j = 0; j < 8; j++) o.u[j] = f2b(out8[j]);
            *reinterpret_cast<uint4*>(&x[(unsigned)n * 128u + lane * 8]) = o.v;
        }
        return;
    } else {
        h16x2 hd2[4], a06[4], a04[4], acc2[4];
        float pd;
        {
            uint2 hv = ldrow(n);
            fp8x4_to_h16(hv.x, hd2[0], hd2[1]);
            fp8x4_to_h16(hv.y, hd2[2], hd2[3]);
            float4 av0 = *reinterpret_cast<const float4*>(&a[lane * 8]);
            float4 av1 = *reinterpret_cast<const float4*>(&a[lane * 8 + 4]);
            float aa[8] = {av0.x, av0.y, av0.z, av0.w, av1.x, av1.y, av1.z, av1.w};
            const float L2E = 1.4426950408889634f;
            #pragma unroll
            for (int k = 0; k < 4; k++) {
                a06[k][0] = (_Float16)(aa[2*k]   * (0.6f * L2E));
                a06[k][1] = (_Float16)(aa[2*k+1] * (0.6f * L2E));
                a04[k][0] = (_Float16)(aa[2*k]   * (0.4f * L2E));
                a04[k][1] = (_Float16)(aa[2*k+1] * (0.4f * L2E));
                acc2[k][0] = (_Float16)0.f; acc2[k][1] = (_Float16)0.f;
            }
            float s = 0.f;
            #pragma unroll
            for (int k = 0; k < 4; k++) s = __builtin_amdgcn_fdot2(hd2[k], a06[k], s, false);
            pd = row16_sum(s);
        }

        const float C1 = 0.69314718f, C2 = 0.24022651f, C3 = 0.05550411f;
        float den = 0.f;

        auto process = [&](uint2 sv) {
            h16x2 hs[4];
            fp8x4_to_h16(sv.x, hs[0], hs[1]);
            fp8x4_to_h16(sv.y, hs[2], hs[3]);
            float p0 = 0.f, p1 = 0.f;
            #pragma unroll
            for (int k = 0; k < 2; k++) {
                h16x2 t2 = hs[k] + hd2[k];
                h16x2 at2 = u2h2(h22u(t2) & 0x7FFF7FFFu);
                p0 = __builtin_amdgcn_fdot2(hs[k], a06[k], p0, false);
                p0 = __builtin_amdgcn_fdot2(at2, a04[k], p0, false);
            }
            #pragma unroll
            for (int k = 2; k < 4; k++) {
                h16x2 t2 = hs[k] + hd2[k];
                h16x2 at2 = u2h2(h22u(t2) & 0x7FFF7FFFu);
                p1 = __builtin_amdgcn_fdot2(hs[k], a06[k], p1, false);
                p1 = __builtin_amdgcn_fdot2(at2, a04[k], p1, false);
            }
            float p = row16_sum(p0 + p1) + pd;
            float w = fmaf(p, fmaf(p, fmaf(p, C3, C2), C1), 1.f);
            den += w;
            h16x2 w2 = packf2(w, w);
            #pragma unroll
            for (int k = 0; k < 4; k++) acc2[k] = w2 * hs[k] + acc2[k];
        };

        for (int base = 0; base < cnt; base += 64) {
            int m = min(64, cnt - base);
            int ev = 0;
            if (lane < m) ev = csr_src[row_s + base + lane];
            int s0 = __builtin_amdgcn_readlane(ev, 0);
            int s1 = __builtin_amdgcn_readlane(ev, m > 1 ? 1 : 0);
            uint2 rA = ldrow(s0), rB = ldrow(s1);
            for (int i = 0; i < m; i += 2) {
                {
                    uint2 cur = rA;
                    rA = ldrow(__builtin_amdgcn_readlane(ev, min(i + 2, m - 1)));
                    process(cur);
                }
                if (i + 1 < m) {
                    uint2 cur = rB;
                    rB = ldrow(__builtin_amdgcn_readlane(ev, min(i + 3, m - 1)));
                    process(cur);
                }
            }
        }

        float inv = (den > 0.f) ? 0.25f / den : 0.f;
        float out8[8];
        #pragma unroll
        for (int j = 0; j < 8; j++) {
            float r = (float)acc2[j >> 1][j & 1] * inv;
            r += __shfl_xor(r, 16);
            r += __shfl_xor(r, 32);
            out8[j] = r;
        }
        int d0 = (lane & 15) * 8;
        float4 wv0 = *reinterpret_cast<const float4*>(&wreg[d0]);
        float4 wv1 = *reinterpret_cast<const float4*>(&wreg[d0 + 4]);
        float pdot = out8[0] * wv0.x + out8[1] * wv0.y + out8[2] * wv0.z + out8[3] * wv0.w
                   + out8[4] * wv1.x + out8[5] * wv1.y + out8[6] * wv1.z + out8[7] * wv1.w;
        pdot = row16_sum(pdot);
        if (lane == 0) dots[n] = pdot;
    }
}

// ---------------- h2 = x @ W2 + b2 via MFMA (swapped operands) ----------------
__global__ void __launch_bounds__(256) gemm_kernel(const unsigned short* __restrict__ x,
                                                   const unsigned short* __restrict__ Wb,
                                                   const float* __restrict__ bias,
                                                   unsigned char* __restrict__ hout) {
    int w = threadIdx.x >> 6, l = threadIdx.x & 63;
    int rb = blockIdx.y * 64 + w * 16;
    int cb = blockIdx.x * 64;
    int lr = l & 15, lq = l >> 4;
    f32x4 acc[4] = {};
    int arow = rb + lr;
    bool rok = arow < N_NODES;
    #pragma unroll
    for (int s = 0; s < 4; s++) {
        s16x8 afr = {};
        if (rok) afr = *reinterpret_cast<const s16x8*>(&x[(size_t)arow * 128 + s * 32 + lq * 8]);
        #pragma unroll
        for (int sub = 0; sub < 4; sub++) {
            s16x8 bfr = *reinterpret_cast<const s16x8*>(
                &Wb[(((size_t)(s * 4 + lq) * 512) + cb + sub * 16 + lr) << 3]);
            acc[sub] = __builtin_amdgcn_mfma_f32_16x16x32_bf16(bfr, afr, acc[sub], 0, 0, 0);
        }
    }
    if (!rok) return;
    #pragma unroll
    for (int sub = 0; sub < 4; sub++) {
        int col0 = cb + sub * 16 + lq * 4;
        float4 bb = *reinterpret_cast<const float4*>(&bias[col0]);
        unsigned int pk = __builtin_amdgcn_cvt_pk_fp8_f32(acc[sub][0] + bb.x,
                                                          acc[sub][1] + bb.y, 0, false);
        pk = __builtin_amdgcn_cvt_pk_fp8_f32(acc[sub][2] + bb.z,
                                             acc[sub][3] + bb.w, pk, true);
        *reinterpret_cast<unsigned int*>(&hout[(size_t)arow * 512 + col0]) = pk;
    }
}

// ---------------- pool over per-node dots + fused final (last block) --------
__global__ void __launch_bounds__(256) pool64_kernel(const float* __restrict__ dots,
                                                     const int* __restrict__ gid,
                                                     float* __restrict__ pool,
                                                     int* __restrict__ done,
                                                     float* __restrict__ out) {
    int wave = (blockIdx.x * blockDim.x + threadIdx.x) >> 6;
    int lane = threadIdx.x & 63;
    int n0 = wave * 64;
    if (n0 < N_NODES) {
        int n = n0 + lane;
        int nc = min(n, N_NODES - 1);
        int g = gid[nc];
        float v = (n < N_NODES) ? dots[n] : 0.f;
        int g0 = __shfl(g, 0);
        bool uni = __all(g == g0);
        if (uni) {
            v += __shfl_xor(v, 1);
            v += __shfl_xor(v, 2);
            v += __shfl_xor(v, 4);
            v += __shfl_xor(v, 8);
            v += __shfl_xor(v, 16);
            v += __shfl_xor(v, 32);
            if (lane == 0) atomicAdd(&pool[g0], v);
        } else {
            if (n < N_NODES) atomicAdd(&pool[g], v);   // rare boundary wave
        }
    }
    __threadfence();
    __syncthreads();
    __shared__ int amlast;
    if (threadIdx.x == 0)
        amlast = (atomicAdd(done, 1) == (int)gridDim.x - 1) ? 1 : 0;
    __syncthreads();
    if (amlast && threadIdx.x < G_GRAPHS) {
        out[threadIdx.x] = atomicAdd(&pool[threadIdx.x], 0.f);
    }
}

extern "C" void kernel_launch(void* const* d_in, const int* in_sizes, int n_in,
                              void* d_out, int out_size, void* d_ws, size_t ws_size,
                              hipStream_t stream) {
    const int* feats = (const int*)d_in[0];
    const int* src   = (const int*)d_in[1];
    const int* dst   = (const int*)d_in[2];
    const int* gids  = (const int*)d_in[3];
    const float* emb  = (const float*)d_in[4];
    const float* W1   = (const float*)d_in[5];
    const float* b1   = (const float*)d_in[6];
    const float* a1   = (const float*)d_in[7];
    const float* W2   = (const float*)d_in[8];
    const float* b2   = (const float*)d_in[9];
    const float* a2   = (const float*)d_in[10];
    const float* wreg = (const float*)d_in[11];
    float* out = (float*)d_out;

    char* ws = (char*)d_ws;
    size_t off = 0;
    auto alloc = [&](size_t bytes) -> void* {
        void* p = ws + off;
        off = (off + bytes + 255) & ~(size_t)255;
        return p;
    };
    // counts + flag + done live in one memset-covered region
    int*   counts  = (int*)alloc((size_t)N_NODES * 4 + 8);
    int*   flag    = counts + N_NODES;       // scanF sync counter
    int*   done    = counts + N_NODES + 1;   // pool64 completion counter
    int*   offsets = (int*)alloc((size_t)(N_NODES + 1) * 4);
    int*   cursor  = (int*)alloc((size_t)N_NODES * 4);
    int*   csr_src = (int*)alloc((size_t)N_EDGES * 4);
    int*   bsum    = (int*)alloc(64 * 4);
    unsigned int*   M1b = (unsigned int*)alloc((size_t)V_VOCAB * HD);     // fp8, 64KB
    unsigned int*   h  = (unsigned int*)alloc((size_t)N_NODES * HD);      // fp8 (layer2)
    unsigned short* x  = (unsigned short*)alloc((size_t)N_NODES * D_DIM * 2);
    unsigned short* Wb = (unsigned short*)alloc((size_t)D_DIM * HD * 2);
    float* Wtab    = (float*)alloc((size_t)V_VOCAB * V_VOCAB * H_HEADS * 4); // 256KB
    float* dots    = (float*)alloc((size_t)N_NODES * 4);
    float* pool    = (float*)alloc((size_t)G_GRAPHS * 4);

    hipMemsetAsync(counts, 0, (size_t)N_NODES * 4 + 8, stream);

    mega_kernel<<<MEGA_M1_BLOCKS + MEGA_WSZ_BLOCKS + MEGA_HIST_BLOCKS, 256, 0, stream>>>(
        emb, W1, b1, M1b, W2, Wb, dst, counts, pool);
    wtab_kernel<<<(V_VOCAB * V_VOCAB) / 4, 256, 0, stream>>>(M1b, a1, Wtab);
    scanf_kernel<<<64, 256, 0, stream>>>(counts, offsets, cursor, bsum, flag);
    scatter_kernel<<<(N_EDGES + 255) / 256, 256, 0, stream>>>(src, dst, cursor, csr_src);

    gat_kernel<true><<<(N_NODES + 3) / 4, 256, 0, stream>>>(M1b, offsets, csr_src, feats,
                                                            a1, wreg, Wtab, x, dots);
    gemm_kernel<<<dim3(8, (N_NODES + 63) / 64), 256, 0, stream>>>(x, Wb, b2, (unsigned char*)h);
    gat_kernel<false><<<(N_NODES + 3) / 4, 256, 0, stream>>>(h, offsets, csr_src, feats,
                                                             a2, wreg, Wtab, x, dots);

    pool64_kernel<<<(N_NODES / 64 + 4) / 4, 256, 0, stream>>>(dots, gids, pool, done, out);
}